// Round 5
// baseline (604.259 us; speedup 1.0000x reference)
//
#include <hip/hip_runtime.h>
#include <hip/hip_bf16.h>

// Problem constants
#define Sq 256
#define Hd 4096
#define NH 128
#define Pd 64
#define Gg 8
#define Nn 128
#define D_INNER 8192            // NH*P
#define D_STATE 1024            // G*N
#define CONV_DIM 10240          // D_INNER + 2*D_STATE
#define IN_OUT 18560            // D_INNER + CONV_DIM + NH
#define DT_COL0 18432           // D_INNER + CONV_DIM (start of dt columns)
#define EPSI 1e-6f

typedef _Float16 f16x8 __attribute__((ext_vector_type(8)));
typedef float f32x4 __attribute__((ext_vector_type(4)));

__device__ inline ushort f2h(float f) {
  _Float16 h = (_Float16)f;
  return __builtin_bit_cast(ushort, h);
}
__device__ inline ushort f2h_lo(float f, ushort hi) {
  float hf = (float)__builtin_bit_cast(_Float16, hi);
  _Float16 l = (_Float16)(f - hf);
  return __builtin_bit_cast(ushort, l);
}

// ---------------- RMSNorm (input) -> fp16 hi + lo ----------------
__global__ __launch_bounds__(256) void rmsnorm_k(const float* __restrict__ x,
                                                 const float* __restrict__ w,
                                                 ushort* __restrict__ h_hi,
                                                 ushort* __restrict__ h_lo) {
  int s = blockIdx.x, t = threadIdx.x;
  const float4* row = reinterpret_cast<const float4*>(x + (size_t)s * Hd);
  const float4* wv  = reinterpret_cast<const float4*>(w);
  float4 v[4];
  float ss = 0.f;
#pragma unroll
  for (int i = 0; i < 4; i++) {
    v[i] = row[t + i * 256];
    ss += v[i].x * v[i].x + v[i].y * v[i].y + v[i].z * v[i].z + v[i].w * v[i].w;
  }
#pragma unroll
  for (int off = 32; off > 0; off >>= 1) ss += __shfl_xor(ss, off);
  __shared__ float red[4];
  if ((t & 63) == 0) red[t >> 6] = ss;
  __syncthreads();
  ss = red[0] + red[1] + red[2] + red[3];
  float scale = rsqrtf(ss * (1.f / (float)Hd) + EPSI);
  ushort4* hh = reinterpret_cast<ushort4*>(h_hi + (size_t)s * Hd);
  ushort4* hl = reinterpret_cast<ushort4*>(h_lo + (size_t)s * Hd);
#pragma unroll
  for (int i = 0; i < 4; i++) {
    float4 wi = wv[t + i * 256];
    float f0 = v[i].x * scale * wi.x, f1 = v[i].y * scale * wi.y;
    float f2 = v[i].z * scale * wi.z, f3 = v[i].w * scale * wi.w;
    ushort4 oh, ol;
    oh.x = f2h(f0); ol.x = f2h_lo(f0, oh.x);
    oh.y = f2h(f1); ol.y = f2h_lo(f1, oh.y);
    oh.z = f2h(f2); ol.z = f2h_lo(f2, oh.z);
    oh.w = f2h(f3); ol.w = f2h_lo(f3, oh.w);
    hh[t + i * 256] = oh;
    hl[t + i * 256] = ol;
  }
}

// ---------------- MFMA GEMM, 64x64 tiles, reg-prefetch pipeline ----------
// C[M, ldc] (+z-partial plane) = A_f16[M,K] * f16(B_f32[N,K])^T
// grid: (x = M/64 row tiles [inner -> B-panel L2 reuse], y = col tiles, z = split-K)
template<int BN, bool SPLIT>
__global__ __launch_bounds__(256) void gemm_mfma(const ushort* __restrict__ A_hi,
                                                 const ushort* __restrict__ A_lo,
                                                 const float* __restrict__ B,
                                                 float* __restrict__ C,
                                                 int ldc, int K, int kLen,
                                                 int bcol0, int M) {
  constexpr int BK = 64;
  constexpr int LDA = 72;                       // f16 elems per LDS row (144B stride)
  constexpr int N_REP = BN / 32;                // per-wave 16-col tiles
  constexpr int BQN = (BN == 128) ? 8 : 4;      // float4 loads of B per thread
  __shared__ __align__(16) ushort As[64 * LDA];
  __shared__ __align__(16) ushort Bs[BN * LDA];
  __shared__ __align__(16) ushort AsL[SPLIT ? 64 * LDA : 1];
  __shared__ __align__(16) ushort BsL[SPLIT ? BN * LDA : 1];

  int t = threadIdx.x;
  int wave = t >> 6, lane = t & 63;
  int wr = wave >> 1, wc = wave & 1;
  int frow = lane & 15, fk = (lane >> 4) * 8;
  int rowBase = blockIdx.x * 64;                // row tile (grid-x: consecutive blocks share B panel)
  int bcol = bcol0 + blockIdx.y * BN;           // row index into B
  int ccol = blockIdx.y * BN;                   // col index into C (compact)
  int kStart = blockIdx.z * kLen;
  C += (size_t)blockIdx.z * M * ldc;            // split-K partial plane

  int arow = t >> 2, ak = (t & 3) * 16;
  const ushort* Ap  = A_hi + (size_t)(rowBase + arow) * K + ak;
  const ushort* ApL = SPLIT ? (A_lo + (size_t)(rowBase + arow) * K + ak) : nullptr;

  int brow, bq;
  if constexpr (BN == 128) { brow = t >> 1; bq = (t & 1) * 32; }
  else                     { brow = t >> 2; bq = (t & 3) * 16; }
  const float* Bp = B + (size_t)(bcol + brow) * K + bq;

  f32x4 acc[2][N_REP] = {};
  uint4 aPre[2], aPreL[2];
  float4 bPre[BQN];

  auto loadK = [&](int kk) {
    aPre[0] = *reinterpret_cast<const uint4*>(Ap + kk);
    aPre[1] = *reinterpret_cast<const uint4*>(Ap + kk + 8);
    if constexpr (SPLIT) {
      aPreL[0] = *reinterpret_cast<const uint4*>(ApL + kk);
      aPreL[1] = *reinterpret_cast<const uint4*>(ApL + kk + 8);
    }
#pragma unroll
    for (int j = 0; j < BQN; ++j)
      bPre[j] = *reinterpret_cast<const float4*>(Bp + kk + j * 4);
  };

  loadK(kStart);
  for (int ki = 0; ki < kLen; ki += BK) {
    __syncthreads();
    // ---- LDS writes from prefetch regs ----
    *reinterpret_cast<uint4*>(&As[arow * LDA + ak])     = aPre[0];
    *reinterpret_cast<uint4*>(&As[arow * LDA + ak + 8]) = aPre[1];
    if constexpr (SPLIT) {
      *reinterpret_cast<uint4*>(&AsL[arow * LDA + ak])     = aPreL[0];
      *reinterpret_cast<uint4*>(&AsL[arow * LDA + ak + 8]) = aPreL[1];
    }
    {
      ushort hb[BQN * 4];
      ushort lb[SPLIT ? BQN * 4 : 1];
      const float* bf = reinterpret_cast<const float*>(bPre);
#pragma unroll
      for (int j = 0; j < BQN * 4; ++j) {
        hb[j] = f2h(bf[j]);
        if constexpr (SPLIT) lb[j] = f2h_lo(bf[j], hb[j]);
      }
#pragma unroll
      for (int j = 0; j < BQN / 2; ++j)
        *reinterpret_cast<uint4*>(&Bs[brow * LDA + bq + j * 8]) =
            reinterpret_cast<const uint4*>(hb)[j];
      if constexpr (SPLIT) {
#pragma unroll
        for (int j = 0; j < BQN / 2; ++j)
          *reinterpret_cast<uint4*>(&BsL[brow * LDA + bq + j * 8]) =
              reinterpret_cast<const uint4*>(lb)[j];
      }
    }
    __syncthreads();
    // ---- prefetch next K-step (overlaps frag reads + MFMA) ----
    if (ki + BK < kLen) loadK(kStart + ki + BK);
    // ---- fragments + MFMA ----
    f16x8 af[2][2], bfv[N_REP][2];
    f16x8 afL[SPLIT ? 2 : 1][2], bfL[SPLIT ? N_REP : 1][2];
#pragma unroll
    for (int m = 0; m < 2; ++m)
#pragma unroll
      for (int kh = 0; kh < 2; ++kh) {
        af[m][kh] = *reinterpret_cast<const f16x8*>(
            &As[(wr * 32 + m * 16 + frow) * LDA + kh * 32 + fk]);
        if constexpr (SPLIT)
          afL[m][kh] = *reinterpret_cast<const f16x8*>(
              &AsL[(wr * 32 + m * 16 + frow) * LDA + kh * 32 + fk]);
      }
#pragma unroll
    for (int n = 0; n < N_REP; ++n)
#pragma unroll
      for (int kh = 0; kh < 2; ++kh) {
        bfv[n][kh] = *reinterpret_cast<const f16x8*>(
            &Bs[(wc * (BN / 2) + n * 16 + frow) * LDA + kh * 32 + fk]);
        if constexpr (SPLIT)
          bfL[n][kh] = *reinterpret_cast<const f16x8*>(
              &BsL[(wc * (BN / 2) + n * 16 + frow) * LDA + kh * 32 + fk]);
      }
#pragma unroll
    for (int kh = 0; kh < 2; ++kh)
#pragma unroll
      for (int m = 0; m < 2; ++m)
#pragma unroll
        for (int n = 0; n < N_REP; ++n) {
          acc[m][n] = __builtin_amdgcn_mfma_f32_16x16x32_f16(af[m][kh], bfv[n][kh], acc[m][n], 0, 0, 0);
          if constexpr (SPLIT) {
            acc[m][n] = __builtin_amdgcn_mfma_f32_16x16x32_f16(af[m][kh], bfL[n][kh], acc[m][n], 0, 0, 0);
            acc[m][n] = __builtin_amdgcn_mfma_f32_16x16x32_f16(afL[m][kh], bfv[n][kh], acc[m][n], 0, 0, 0);
          }
        }
  }

  // ---- epilogue: C/D layout col=lane&15, row=(lane>>4)*4+r ----
#pragma unroll
  for (int m = 0; m < 2; ++m) {
    int row0 = rowBase + wr * 32 + m * 16 + (lane >> 4) * 4;
#pragma unroll
    for (int n = 0; n < N_REP; ++n) {
      int col = ccol + wc * (BN / 2) + n * 16 + frow;
#pragma unroll
      for (int r = 0; r < 4; ++r)
        C[(size_t)(row0 + r) * ldc + col] = acc[m][n][r];
    }
  }
}

// ---------------- Conv (K=4) + SiLU ----------------
__global__ __launch_bounds__(256) void conv_silu_k(const float* __restrict__ proj,
                                                   const float* __restrict__ cstate,
                                                   const float* __restrict__ cw,
                                                   const float* __restrict__ cb,
                                                   float* __restrict__ y) {
  int c = blockIdx.x * 256 + threadIdx.x;  // 0..10239
  int s = blockIdx.y;                      // 0..255
  float acc = cb[c];
  float4 w4 = *reinterpret_cast<const float4*>(cw + c * 4);
  float wj[4] = {w4.x, w4.y, w4.z, w4.w};
#pragma unroll
  for (int j = 0; j < 4; j++) {
    int si = s + j - 3;
    float v = (si < 0) ? cstate[c * 3 + (si + 3)]
                       : proj[(size_t)si * IN_OUT + D_INNER + c];
    acc += wj[j] * v;
  }
  float sig = 1.f / (1.f + expf(-acc));
  y[(size_t)s * CONV_DIM + c] = acc * sig;
}

// ---------------- conv_state_out ----------------
__global__ __launch_bounds__(256) void conv_state_out_k(const float* __restrict__ proj,
                                                        float* __restrict__ out1) {
  int idx = blockIdx.x * 256 + threadIdx.x;  // < 30720
  int c = idx / 3, tt = idx % 3;
  out1[idx] = proj[(size_t)(Sq - 3 + tt) * IN_OUT + D_INNER + c];
}

// ---------------- dt: reduce 4 split-K partials + bias -> softplus ----------------
__global__ __launch_bounds__(256) void dt_k(const float* __restrict__ dtfix,
                                            const float* __restrict__ dt_bias,
                                            float* __restrict__ dtp) {
  int idx = blockIdx.x * 256 + threadIdx.x;  // 32768 = 256*128
  int hh = idx & 127;
  float v = dtfix[idx] + dtfix[32768 + idx] + dtfix[65536 + idx] + dtfix[98304 + idx]
            + dt_bias[hh];
  dtp[idx] = (v > 20.f) ? v : log1pf(expf(v));
}

// ---------------- SSM scan (chunked LDS staging, 2 blocks per head) ----------------
// Block = (head, p-half). 256 threads: t -> pl = t>>3 (local p 0..31), ng = t&7 (16 n's).
#define CS 16
__global__ __launch_bounds__(256) void ssm_scan_k(const float* __restrict__ y_conv,
                                                  const float* __restrict__ dtp,
                                                  const float* __restrict__ sstate_in,
                                                  const float* __restrict__ A_log,
                                                  const float* __restrict__ D_param,
                                                  float* __restrict__ ys_out,
                                                  float* __restrict__ sstate_out) {
  int h = blockIdx.x >> 1;
  int pb = (blockIdx.x & 1) * 32;
  int t = threadIdx.x;
  int ng = t & 7, pl = t >> 3;
  int g = h >> 4;  // rep = NH/G = 16
  float A = -expf(A_log[h]);
  float Dp = D_param[h];

  float st[16];
  {
    const float* sp = sstate_in + ((size_t)h * Pd + pb + pl) * Nn + ng * 16;
#pragma unroll
    for (int i = 0; i < 16; i += 4) {
      float4 v = *reinterpret_cast<const float4*>(sp + i);
      st[i] = v.x; st[i + 1] = v.y; st[i + 2] = v.z; st[i + 3] = v.w;
    }
  }

  __shared__ float ybuf[CS][296];   // [0..31]=x(local), [32..159]=B, [160..287]=C
  __shared__ float dts[CS];
  int lr = t >> 4;       // 0..15 : chunk row this thread stages
  int lc = t & 15;       // f4-col worker

  for (int ch = 0; ch < Sq / CS; ++ch) {
    int s0 = ch * CS;
    __syncthreads();
    const float* rowp = y_conv + (size_t)(s0 + lr) * CONV_DIM;
#pragma unroll
    for (int j = 0; j < 5; ++j) {
      int c = lc + 16 * j;  // f4 index 0..79 (72 used)
      if (c < 72) {
        const float* src;
        if (c < 8)       src = rowp + h * 64 + pb + c * 4;
        else if (c < 40) src = rowp + D_INNER + g * 128 + (c - 8) * 4;
        else             src = rowp + D_INNER + D_STATE + g * 128 + (c - 40) * 4;
        *reinterpret_cast<float4*>(&ybuf[lr][c * 4]) = *reinterpret_cast<const float4*>(src);
      }
    }
    if (t < CS) dts[t] = dtp[(s0 + t) * NH + h];
    __syncthreads();

#pragma unroll 4
    for (int stp = 0; stp < CS; ++stp) {
      float dt = dts[stp];
      float dA = expf(dt * A);
      float x0 = ybuf[stp][pl];
      float dtx = dt * x0;
      float y0 = 0.f;
#pragma unroll
      for (int i = 0; i < 16; ++i) {
        float b = ybuf[stp][32 + ng * 16 + i];
        float c = ybuf[stp][160 + ng * 16 + i];
        st[i] = st[i] * dA + dtx * b;
        y0 += st[i] * c;
      }
      y0 += __shfl_xor(y0, 1); y0 += __shfl_xor(y0, 2); y0 += __shfl_xor(y0, 4);
      if (ng == 0)
        ys_out[(size_t)(s0 + stp) * D_INNER + h * 64 + pb + pl] = y0 + Dp * x0;
    }
  }

  float* so = sstate_out + ((size_t)h * Pd + pb + pl) * Nn + ng * 16;
#pragma unroll
  for (int i = 0; i < 16; i += 4)
    *reinterpret_cast<float4*>(so + i) = make_float4(st[i], st[i + 1], st[i + 2], st[i + 3]);
}

// ---------------- gate*silu + grouped RMSNorm -> fp16 ----------------
__global__ __launch_bounds__(256) void gated_norm_k(const float* __restrict__ ys,
                                                    const float* __restrict__ proj,
                                                    const float* __restrict__ w,
                                                    ushort* __restrict__ out_h) {
  int s = blockIdx.x, g = blockIdx.y, t = threadIdx.x;
  float vals[4];
  float ss = 0.f;
#pragma unroll
  for (int i = 0; i < 4; i++) {
    int d = g * 1024 + i * 256 + t;
    float gate = proj[(size_t)s * IN_OUT + d];
    float v = ys[(size_t)s * D_INNER + d] * (gate / (1.f + expf(-gate)));
    vals[i] = v;
    ss += v * v;
  }
#pragma unroll
  for (int off = 32; off > 0; off >>= 1) ss += __shfl_xor(ss, off);
  __shared__ float red[4];
  if ((t & 63) == 0) red[t >> 6] = ss;
  __syncthreads();
  ss = red[0] + red[1] + red[2] + red[3];
  float scale = rsqrtf(ss * (1.f / 1024.f) + EPSI);
#pragma unroll
  for (int i = 0; i < 4; i++) {
    int d = g * 1024 + i * 256 + t;
    out_h[(size_t)s * D_INNER + d] = f2h(vals[i] * scale * w[d]);
  }
}

// ---------------- out reduce: out0 = p0+p1+p2+p3 + hidden ----------------
__global__ __launch_bounds__(256) void reduce_out_k(const float* __restrict__ p,
                                                    const float* __restrict__ hidden,
                                                    float* __restrict__ out0) {
  int i = blockIdx.x * 256 + threadIdx.x;   // f4 index, 262144 total
  const int PL = Sq * Hd / 4;               // plane stride in float4
  float4 a = reinterpret_cast<const float4*>(p)[i];
  float4 b = reinterpret_cast<const float4*>(p)[i + PL];
  float4 c = reinterpret_cast<const float4*>(p)[i + 2 * PL];
  float4 d = reinterpret_cast<const float4*>(p)[i + 3 * PL];
  float4 e = reinterpret_cast<const float4*>(hidden)[i];
  float4 o;
  o.x = a.x + b.x + c.x + d.x + e.x;
  o.y = a.y + b.y + c.y + d.y + e.y;
  o.z = a.z + b.z + c.z + d.z + e.z;
  o.w = a.w + b.w + c.w + d.w + e.w;
  reinterpret_cast<float4*>(out0)[i] = o;
}

extern "C" void kernel_launch(void* const* d_in, const int* in_sizes, int n_in,
                              void* d_out, int out_size, void* d_ws, size_t ws_size,
                              hipStream_t stream) {
  const float* hidden    = (const float*)d_in[0];
  const float* cstate_in = (const float*)d_in[1];
  const float* sstate_in = (const float*)d_in[2];
  const float* norm_w    = (const float*)d_in[3];
  const float* w_in      = (const float*)d_in[4];
  const float* conv_w    = (const float*)d_in[5];
  const float* conv_b    = (const float*)d_in[6];
  const float* A_log     = (const float*)d_in[7];
  const float* D_param   = (const float*)d_in[8];
  const float* dt_bias   = (const float*)d_in[9];
  const float* ssm_nw    = (const float*)d_in[10];
  const float* w_out     = (const float*)d_in[11];

  float* out0 = (float*)d_out;                    // [256,4096]
  float* out1 = out0 + (size_t)Sq * Hd;           // [10240,3]
  float* out2 = out1 + (size_t)CONV_DIM * 3;      // [128,64,128]

  ushort* h_hi  = (ushort*)d_ws;                              // 2 MB
  ushort* h_lo  = h_hi + (size_t)Sq * Hd;                     // 2 MB
  float* proj   = (float*)(h_lo + (size_t)Sq * Hd);           // 19 MB
  float* y_conv = proj + (size_t)Sq * IN_OUT;                 // 10.5 MB
  float* dtp    = y_conv + (size_t)Sq * CONV_DIM;             // 128 KB
  float* ys     = dtp + (size_t)Sq * NH;                      // 8 MB
  ushort* ys_h  = (ushort*)(ys + (size_t)Sq * D_INNER);       // 4 MB
  float* dtfix  = (float*)(ys_h + (size_t)Sq * D_INNER);      // 512 KB
  float* oppart = proj;   // out_proj partials alias proj (dead after gated_norm_k)

  // 1. RMSNorm -> fp16 hi/lo
  rmsnorm_k<<<Sq, 256, 0, stream>>>(hidden, norm_w, h_hi, h_lo);
  // 2. in_proj: proj[256,18560] = h @ w_in^T   (1160 blocks, row-tiles inner for B reuse)
  gemm_mfma<64, false><<<dim3(4, IN_OUT / 64, 1), 256, 0, stream>>>(
      h_hi, nullptr, w_in, proj, IN_OUT, Hd, Hd, 0, Sq);
  // 2b. dt columns, compensated fp16 (~f32), split-K x4 -> dtfix partials (32 blocks)
  gemm_mfma<64, true><<<dim3(4, 2, 4), 256, 0, stream>>>(
      h_hi, h_lo, w_in, dtfix, NH, Hd, Hd / 4, DT_COL0, Sq);
  // 3. conv + silu
  conv_silu_k<<<dim3(CONV_DIM / 256, Sq), 256, 0, stream>>>(proj, cstate_in, conv_w, conv_b, y_conv);
  // 4. conv_state_out
  conv_state_out_k<<<(CONV_DIM * 3) / 256, 256, 0, stream>>>(proj, out1);
  // 5. dt: reduce partials + softplus
  dt_k<<<(Sq * NH) / 256, 256, 0, stream>>>(dtfix, dt_bias, dtp);
  // 6. SSM scan (2 blocks per head)
  ssm_scan_k<<<NH * 2, 256, 0, stream>>>(y_conv, dtp, sstate_in, A_log, D_param, ys, out2);
  // 7. gated + grouped RMSNorm -> fp16 A for out_proj  (proj dead after this)
  gated_norm_k<<<dim3(Sq, Gg), 256, 0, stream>>>(ys, proj, ssm_nw, ys_h);
  // 8. out_proj split-K x4 -> partials (1024 blocks), into aliased proj space
  gemm_mfma<64, false><<<dim3(4, Hd / 64, 4), 256, 0, stream>>>(
      ys_h, nullptr, w_out, oppart, Hd, D_INNER, D_INNER / 4, 0, Sq);
  // 9. reduce 4 partials + residual
  reduce_out_k<<<(Sq * Hd / 4) / 256, 256, 0, stream>>>(oppart, hidden, out0);
}

// Round 6
// 543.998 us; speedup vs baseline: 1.1108x; 1.1108x over previous
//
#include <hip/hip_runtime.h>
#include <hip/hip_bf16.h>

// Problem constants
#define Sq 256
#define Hd 4096
#define NH 128
#define Pd 64
#define Gg 8
#define Nn 128
#define D_INNER 8192            // NH*P
#define D_STATE 1024            // G*N
#define CONV_DIM 10240          // D_INNER + 2*D_STATE
#define IN_OUT 18560            // D_INNER + CONV_DIM + NH
#define DT_COL0 18432           // D_INNER + CONV_DIM (start of dt columns)
#define EPSI 1e-6f

typedef _Float16 f16x8 __attribute__((ext_vector_type(8)));
typedef float f32x4 __attribute__((ext_vector_type(4)));

__device__ inline ushort f2h(float f) {
  _Float16 h = (_Float16)f;
  return __builtin_bit_cast(ushort, h);
}
__device__ inline ushort f2h_lo(float f, ushort hi) {
  float hf = (float)__builtin_bit_cast(_Float16, hi);
  _Float16 l = (_Float16)(f - hf);
  return __builtin_bit_cast(ushort, l);
}

// ---------------- RMSNorm (input) -> fp16 hi + lo ----------------
__global__ __launch_bounds__(256) void rmsnorm_k(const float* __restrict__ x,
                                                 const float* __restrict__ w,
                                                 ushort* __restrict__ h_hi,
                                                 ushort* __restrict__ h_lo) {
  int s = blockIdx.x, t = threadIdx.x;
  const float4* row = reinterpret_cast<const float4*>(x + (size_t)s * Hd);
  const float4* wv  = reinterpret_cast<const float4*>(w);
  float4 v[4];
  float ss = 0.f;
#pragma unroll
  for (int i = 0; i < 4; i++) {
    v[i] = row[t + i * 256];
    ss += v[i].x * v[i].x + v[i].y * v[i].y + v[i].z * v[i].z + v[i].w * v[i].w;
  }
#pragma unroll
  for (int off = 32; off > 0; off >>= 1) ss += __shfl_xor(ss, off);
  __shared__ float red[4];
  if ((t & 63) == 0) red[t >> 6] = ss;
  __syncthreads();
  ss = red[0] + red[1] + red[2] + red[3];
  float scale = rsqrtf(ss * (1.f / (float)Hd) + EPSI);
  ushort4* hh = reinterpret_cast<ushort4*>(h_hi + (size_t)s * Hd);
  ushort4* hl = reinterpret_cast<ushort4*>(h_lo + (size_t)s * Hd);
#pragma unroll
  for (int i = 0; i < 4; i++) {
    float4 wi = wv[t + i * 256];
    float f0 = v[i].x * scale * wi.x, f1 = v[i].y * scale * wi.y;
    float f2 = v[i].z * scale * wi.z, f3 = v[i].w * scale * wi.w;
    ushort4 oh, ol;
    oh.x = f2h(f0); ol.x = f2h_lo(f0, oh.x);
    oh.y = f2h(f1); ol.y = f2h_lo(f1, oh.y);
    oh.z = f2h(f2); ol.z = f2h_lo(f2, oh.z);
    oh.w = f2h(f3); ol.w = f2h_lo(f3, oh.w);
    hh[t + i * 256] = oh;
    hl[t + i * 256] = ol;
  }
}

// ================= Streaming MFMA GEMM with raw-barrier depth-2 pipeline ======
// C[M,ldc](+z plane) = A_f16[M,K] * f16(B_f32[N,K])^T
// BM=128, BN=64, BK=64. 256 threads = 4 waves (2r x 2c), wave tile 64x32.
// blockIdx.x = coltile*2 + rowtile (paired so B-panel sharers are co-resident).
// Depth-2 register ring; raw s_barrier (no vmcnt drain) -> loads stay in flight.
__global__ __launch_bounds__(256) void gemm_stream(const ushort* __restrict__ A,
                                                   const float* __restrict__ B,
                                                   float* __restrict__ C,
                                                   int ldc, int K, int kLen, int M) {
  constexpr int BK = 64, LDA = 72;
  __shared__ __align__(16) ushort As[2][128 * LDA];
  __shared__ __align__(16) ushort Bs[2][64 * LDA];
  int t = threadIdx.x;
  int wave = t >> 6, lane = t & 63;
  int wr = wave >> 1, wc = wave & 1;
  int frow = lane & 15, fk = (lane >> 4) * 8;
  int coltile = blockIdx.x >> 1;
  int rowBase = (blockIdx.x & 1) * 128;
  int bcol = coltile * 64;
  int kStart = blockIdx.z * kLen;
  C += (size_t)blockIdx.z * M * ldc;

  int arow = t >> 1, ak = (t & 1) * 32;
  const ushort* Ap = A + (size_t)(rowBase + arow) * K + kStart + ak;
  int brow = t >> 2, bk = (t & 3) * 16;
  const float* Bp = B + (size_t)(bcol + brow) * K + kStart + bk;

  uint4 ra0[4], ra1[4];
  float4 rb0[4], rb1[4];
  f32x4 acc[4][2] = {};
  const int NT = kLen / BK;

#define ISSUE0(kk) { _Pragma("unroll") for (int j = 0; j < 4; ++j) ra0[j] = *(const uint4*)(Ap + (kk) + j * 8); \
                     _Pragma("unroll") for (int j = 0; j < 4; ++j) rb0[j] = *(const float4*)(Bp + (kk) + j * 4); }
#define ISSUE1(kk) { _Pragma("unroll") for (int j = 0; j < 4; ++j) ra1[j] = *(const uint4*)(Ap + (kk) + j * 8); \
                     _Pragma("unroll") for (int j = 0; j < 4; ++j) rb1[j] = *(const float4*)(Bp + (kk) + j * 4); }
#define STAGE(P) { \
    ushort hb[16]; \
    _Pragma("unroll") for (int j = 0; j < 4; ++j) { \
      hb[j*4+0] = f2h(rb##P[j].x); hb[j*4+1] = f2h(rb##P[j].y); \
      hb[j*4+2] = f2h(rb##P[j].z); hb[j*4+3] = f2h(rb##P[j].w); } \
    *(uint4*)(&Bs[P][brow * LDA + bk])     = ((uint4*)hb)[0]; \
    *(uint4*)(&Bs[P][brow * LDA + bk + 8]) = ((uint4*)hb)[1]; \
    _Pragma("unroll") for (int j = 0; j < 4; ++j) \
      *(uint4*)(&As[P][arow * LDA + ak + j * 8]) = ra##P[j]; }
#define COMPUTE(P) { \
    f16x8 af[4][2], bf[2][2]; \
    _Pragma("unroll") for (int m = 0; m < 4; ++m) \
      _Pragma("unroll") for (int kh = 0; kh < 2; ++kh) \
        af[m][kh] = *(const f16x8*)(&As[P][(wr * 64 + m * 16 + frow) * LDA + kh * 32 + fk]); \
    _Pragma("unroll") for (int n = 0; n < 2; ++n) \
      _Pragma("unroll") for (int kh = 0; kh < 2; ++kh) \
        bf[n][kh] = *(const f16x8*)(&Bs[P][(wc * 32 + n * 16 + frow) * LDA + kh * 32 + fk]); \
    _Pragma("unroll") for (int kh = 0; kh < 2; ++kh) \
      _Pragma("unroll") for (int m = 0; m < 4; ++m) \
        _Pragma("unroll") for (int n = 0; n < 2; ++n) \
          acc[m][n] = __builtin_amdgcn_mfma_f32_16x16x32_f16(af[m][kh], bf[n][kh], acc[m][n], 0, 0, 0); }
#define BAR() { asm volatile("s_waitcnt lgkmcnt(0)" ::: "memory"); \
                __builtin_amdgcn_sched_barrier(0); \
                __builtin_amdgcn_s_barrier(); \
                __builtin_amdgcn_sched_barrier(0); }

  // Prologue: tiles 0,1 issued; tile0 staged; tile2 issued. lds[0]=t0 ready.
  ISSUE0(0)
  ISSUE1(BK)
  STAGE(0)
  ISSUE0(2 * BK)
  BAR()
  for (int i = 0; i < NT; i += 2) {
    COMPUTE(0)                               // tile i from lds[0]
    STAGE(1)                                 // tile i+1 -> lds[1] (vmcnt(8) auto)
    if (i + 3 < NT) ISSUE1((i + 3) * BK)
    BAR()
    COMPUTE(1)                               // tile i+1 from lds[1]
    if (i + 2 < NT) {
      STAGE(0)                               // tile i+2 -> lds[0]
      if (i + 4 < NT) ISSUE0((i + 4) * BK)
      BAR()
    }
  }
#undef ISSUE0
#undef ISSUE1
#undef STAGE
#undef COMPUTE
#undef BAR

  // Epilogue: C/D layout col=lane&15, row=(lane>>4)*4+r
#pragma unroll
  for (int m = 0; m < 4; ++m) {
    int row0 = rowBase + wr * 64 + m * 16 + (lane >> 4) * 4;
#pragma unroll
    for (int n = 0; n < 2; ++n) {
      int col = bcol + wc * 32 + n * 16 + frow;
#pragma unroll
      for (int r = 0; r < 4; ++r)
        C[(size_t)(row0 + r) * ldc + col] = acc[m][n][r];
    }
  }
}

// ---------------- old-style MFMA GEMM (kept for dt-fixup, compensated fp16) ----
template<int BN, bool SPLIT>
__global__ __launch_bounds__(256) void gemm_mfma(const ushort* __restrict__ A_hi,
                                                 const ushort* __restrict__ A_lo,
                                                 const float* __restrict__ B,
                                                 float* __restrict__ C,
                                                 int ldc, int K, int kLen,
                                                 int bcol0, int M) {
  constexpr int BK = 64;
  constexpr int LDA = 72;
  constexpr int N_REP = BN / 32;
  constexpr int BQN = (BN == 128) ? 8 : 4;
  __shared__ __align__(16) ushort As[64 * LDA];
  __shared__ __align__(16) ushort Bs[BN * LDA];
  __shared__ __align__(16) ushort AsL[SPLIT ? 64 * LDA : 1];
  __shared__ __align__(16) ushort BsL[SPLIT ? BN * LDA : 1];

  int t = threadIdx.x;
  int wave = t >> 6, lane = t & 63;
  int wr = wave >> 1, wc = wave & 1;
  int frow = lane & 15, fk = (lane >> 4) * 8;
  int rowBase = blockIdx.x * 64;
  int bcol = bcol0 + blockIdx.y * BN;
  int ccol = blockIdx.y * BN;
  int kStart = blockIdx.z * kLen;
  C += (size_t)blockIdx.z * M * ldc;

  int arow = t >> 2, ak = (t & 3) * 16;
  const ushort* Ap  = A_hi + (size_t)(rowBase + arow) * K + ak;
  const ushort* ApL = SPLIT ? (A_lo + (size_t)(rowBase + arow) * K + ak) : nullptr;

  int brow, bq;
  if constexpr (BN == 128) { brow = t >> 1; bq = (t & 1) * 32; }
  else                     { brow = t >> 2; bq = (t & 3) * 16; }
  const float* Bp = B + (size_t)(bcol + brow) * K + bq;

  f32x4 acc[2][N_REP] = {};
  uint4 aPre[2], aPreL[2];
  float4 bPre[BQN];

  auto loadK = [&](int kk) {
    aPre[0] = *reinterpret_cast<const uint4*>(Ap + kk);
    aPre[1] = *reinterpret_cast<const uint4*>(Ap + kk + 8);
    if constexpr (SPLIT) {
      aPreL[0] = *reinterpret_cast<const uint4*>(ApL + kk);
      aPreL[1] = *reinterpret_cast<const uint4*>(ApL + kk + 8);
    }
#pragma unroll
    for (int j = 0; j < BQN; ++j)
      bPre[j] = *reinterpret_cast<const float4*>(Bp + kk + j * 4);
  };

  loadK(kStart);
  for (int ki = 0; ki < kLen; ki += BK) {
    __syncthreads();
    *reinterpret_cast<uint4*>(&As[arow * LDA + ak])     = aPre[0];
    *reinterpret_cast<uint4*>(&As[arow * LDA + ak + 8]) = aPre[1];
    if constexpr (SPLIT) {
      *reinterpret_cast<uint4*>(&AsL[arow * LDA + ak])     = aPreL[0];
      *reinterpret_cast<uint4*>(&AsL[arow * LDA + ak + 8]) = aPreL[1];
    }
    {
      ushort hb[BQN * 4];
      ushort lb[SPLIT ? BQN * 4 : 1];
      const float* bf = reinterpret_cast<const float*>(bPre);
#pragma unroll
      for (int j = 0; j < BQN * 4; ++j) {
        hb[j] = f2h(bf[j]);
        if constexpr (SPLIT) lb[j] = f2h_lo(bf[j], hb[j]);
      }
#pragma unroll
      for (int j = 0; j < BQN / 2; ++j)
        *reinterpret_cast<uint4*>(&Bs[brow * LDA + bq + j * 8]) =
            reinterpret_cast<const uint4*>(hb)[j];
      if constexpr (SPLIT) {
#pragma unroll
        for (int j = 0; j < BQN / 2; ++j)
          *reinterpret_cast<uint4*>(&BsL[brow * LDA + bq + j * 8]) =
              reinterpret_cast<const uint4*>(lb)[j];
      }
    }
    __syncthreads();
    if (ki + BK < kLen) loadK(kStart + ki + BK);
    f16x8 af[2][2], bfv[N_REP][2];
    f16x8 afL[SPLIT ? 2 : 1][2], bfL[SPLIT ? N_REP : 1][2];
#pragma unroll
    for (int m = 0; m < 2; ++m)
#pragma unroll
      for (int kh = 0; kh < 2; ++kh) {
        af[m][kh] = *reinterpret_cast<const f16x8*>(
            &As[(wr * 32 + m * 16 + frow) * LDA + kh * 32 + fk]);
        if constexpr (SPLIT)
          afL[m][kh] = *reinterpret_cast<const f16x8*>(
              &AsL[(wr * 32 + m * 16 + frow) * LDA + kh * 32 + fk]);
      }
#pragma unroll
    for (int n = 0; n < N_REP; ++n)
#pragma unroll
      for (int kh = 0; kh < 2; ++kh) {
        bfv[n][kh] = *reinterpret_cast<const f16x8*>(
            &Bs[(wc * (BN / 2) + n * 16 + frow) * LDA + kh * 32 + fk]);
        if constexpr (SPLIT)
          bfL[n][kh] = *reinterpret_cast<const f16x8*>(
              &BsL[(wc * (BN / 2) + n * 16 + frow) * LDA + kh * 32 + fk]);
      }
#pragma unroll
    for (int kh = 0; kh < 2; ++kh)
#pragma unroll
      for (int m = 0; m < 2; ++m)
#pragma unroll
        for (int n = 0; n < N_REP; ++n) {
          acc[m][n] = __builtin_amdgcn_mfma_f32_16x16x32_f16(af[m][kh], bfv[n][kh], acc[m][n], 0, 0, 0);
          if constexpr (SPLIT) {
            acc[m][n] = __builtin_amdgcn_mfma_f32_16x16x32_f16(af[m][kh], bfL[n][kh], acc[m][n], 0, 0, 0);
            acc[m][n] = __builtin_amdgcn_mfma_f32_16x16x32_f16(afL[m][kh], bfv[n][kh], acc[m][n], 0, 0, 0);
          }
        }
  }

#pragma unroll
  for (int m = 0; m < 2; ++m) {
    int row0 = rowBase + wr * 32 + m * 16 + (lane >> 4) * 4;
#pragma unroll
    for (int n = 0; n < N_REP; ++n) {
      int col = ccol + wc * (BN / 2) + n * 16 + frow;
#pragma unroll
      for (int r = 0; r < 4; ++r)
        C[(size_t)(row0 + r) * ldc + col] = acc[m][n][r];
    }
  }
}

// ---------------- Conv (K=4) + SiLU ----------------
__global__ __launch_bounds__(256) void conv_silu_k(const float* __restrict__ proj,
                                                   const float* __restrict__ cstate,
                                                   const float* __restrict__ cw,
                                                   const float* __restrict__ cb,
                                                   float* __restrict__ y) {
  int c = blockIdx.x * 256 + threadIdx.x;  // 0..10239
  int s = blockIdx.y;                      // 0..255
  float acc = cb[c];
  float4 w4 = *reinterpret_cast<const float4*>(cw + c * 4);
  float wj[4] = {w4.x, w4.y, w4.z, w4.w};
#pragma unroll
  for (int j = 0; j < 4; j++) {
    int si = s + j - 3;
    float v = (si < 0) ? cstate[c * 3 + (si + 3)]
                       : proj[(size_t)si * IN_OUT + D_INNER + c];
    acc += wj[j] * v;
  }
  float sig = 1.f / (1.f + expf(-acc));
  y[(size_t)s * CONV_DIM + c] = acc * sig;
}

// ---------------- conv_state_out ----------------
__global__ __launch_bounds__(256) void conv_state_out_k(const float* __restrict__ proj,
                                                        float* __restrict__ out1) {
  int idx = blockIdx.x * 256 + threadIdx.x;  // < 30720
  int c = idx / 3, tt = idx % 3;
  out1[idx] = proj[(size_t)(Sq - 3 + tt) * IN_OUT + D_INNER + c];
}

// ---------------- dt: reduce 4 split-K partials + bias -> softplus ----------------
__global__ __launch_bounds__(256) void dt_k(const float* __restrict__ dtfix,
                                            const float* __restrict__ dt_bias,
                                            float* __restrict__ dtp) {
  int idx = blockIdx.x * 256 + threadIdx.x;  // 32768 = 256*128
  int hh = idx & 127;
  float v = dtfix[idx] + dtfix[32768 + idx] + dtfix[65536 + idx] + dtfix[98304 + idx]
            + dt_bias[hh];
  dtp[idx] = (v > 20.f) ? v : log1pf(expf(v));
}

// ---------------- SSM scan (chunked LDS staging, 2 blocks per head) ----------------
#define CS 16
__global__ __launch_bounds__(256) void ssm_scan_k(const float* __restrict__ y_conv,
                                                  const float* __restrict__ dtp,
                                                  const float* __restrict__ sstate_in,
                                                  const float* __restrict__ A_log,
                                                  const float* __restrict__ D_param,
                                                  float* __restrict__ ys_out,
                                                  float* __restrict__ sstate_out) {
  int h = blockIdx.x >> 1;
  int pb = (blockIdx.x & 1) * 32;
  int t = threadIdx.x;
  int ng = t & 7, pl = t >> 3;
  int g = h >> 4;  // rep = NH/G = 16
  float A = -expf(A_log[h]);
  float Dp = D_param[h];

  float st[16];
  {
    const float* sp = sstate_in + ((size_t)h * Pd + pb + pl) * Nn + ng * 16;
#pragma unroll
    for (int i = 0; i < 16; i += 4) {
      float4 v = *reinterpret_cast<const float4*>(sp + i);
      st[i] = v.x; st[i + 1] = v.y; st[i + 2] = v.z; st[i + 3] = v.w;
    }
  }

  __shared__ float ybuf[CS][296];   // [0..31]=x(local), [32..159]=B, [160..287]=C
  __shared__ float dts[CS];
  int lr = t >> 4;
  int lc = t & 15;

  for (int ch = 0; ch < Sq / CS; ++ch) {
    int s0 = ch * CS;
    __syncthreads();
    const float* rowp = y_conv + (size_t)(s0 + lr) * CONV_DIM;
#pragma unroll
    for (int j = 0; j < 5; ++j) {
      int c = lc + 16 * j;
      if (c < 72) {
        const float* src;
        if (c < 8)       src = rowp + h * 64 + pb + c * 4;
        else if (c < 40) src = rowp + D_INNER + g * 128 + (c - 8) * 4;
        else             src = rowp + D_INNER + D_STATE + g * 128 + (c - 40) * 4;
        *reinterpret_cast<float4*>(&ybuf[lr][c * 4]) = *reinterpret_cast<const float4*>(src);
      }
    }
    if (t < CS) dts[t] = dtp[(s0 + t) * NH + h];
    __syncthreads();

#pragma unroll 4
    for (int stp = 0; stp < CS; ++stp) {
      float dt = dts[stp];
      float dA = expf(dt * A);
      float x0 = ybuf[stp][pl];
      float dtx = dt * x0;
      float y0 = 0.f;
#pragma unroll
      for (int i = 0; i < 16; ++i) {
        float b = ybuf[stp][32 + ng * 16 + i];
        float c = ybuf[stp][160 + ng * 16 + i];
        st[i] = st[i] * dA + dtx * b;
        y0 += st[i] * c;
      }
      y0 += __shfl_xor(y0, 1); y0 += __shfl_xor(y0, 2); y0 += __shfl_xor(y0, 4);
      if (ng == 0)
        ys_out[(size_t)(s0 + stp) * D_INNER + h * 64 + pb + pl] = y0 + Dp * x0;
    }
  }

  float* so = sstate_out + ((size_t)h * Pd + pb + pl) * Nn + ng * 16;
#pragma unroll
  for (int i = 0; i < 16; i += 4)
    *reinterpret_cast<float4*>(so + i) = make_float4(st[i], st[i + 1], st[i + 2], st[i + 3]);
}

// ---------------- gate*silu + grouped RMSNorm -> fp16 ----------------
__global__ __launch_bounds__(256) void gated_norm_k(const float* __restrict__ ys,
                                                    const float* __restrict__ proj,
                                                    const float* __restrict__ w,
                                                    ushort* __restrict__ out_h) {
  int s = blockIdx.x, g = blockIdx.y, t = threadIdx.x;
  float vals[4];
  float ss = 0.f;
#pragma unroll
  for (int i = 0; i < 4; i++) {
    int d = g * 1024 + i * 256 + t;
    float gate = proj[(size_t)s * IN_OUT + d];
    float v = ys[(size_t)s * D_INNER + d] * (gate / (1.f + expf(-gate)));
    vals[i] = v;
    ss += v * v;
  }
#pragma unroll
  for (int off = 32; off > 0; off >>= 1) ss += __shfl_xor(ss, off);
  __shared__ float red[4];
  if ((t & 63) == 0) red[t >> 6] = ss;
  __syncthreads();
  ss = red[0] + red[1] + red[2] + red[3];
  float scale = rsqrtf(ss * (1.f / 1024.f) + EPSI);
#pragma unroll
  for (int i = 0; i < 4; i++) {
    int d = g * 1024 + i * 256 + t;
    out_h[(size_t)s * D_INNER + d] = f2h(vals[i] * scale * w[d]);
  }
}

// ---------------- out reduce: out0 = p0+p1+p2+p3 + hidden ----------------
__global__ __launch_bounds__(256) void reduce_out_k(const float* __restrict__ p,
                                                    const float* __restrict__ hidden,
                                                    float* __restrict__ out0) {
  int i = blockIdx.x * 256 + threadIdx.x;
  const int PL = Sq * Hd / 4;
  float4 a = reinterpret_cast<const float4*>(p)[i];
  float4 b = reinterpret_cast<const float4*>(p)[i + PL];
  float4 c = reinterpret_cast<const float4*>(p)[i + 2 * PL];
  float4 d = reinterpret_cast<const float4*>(p)[i + 3 * PL];
  float4 e = reinterpret_cast<const float4*>(hidden)[i];
  float4 o;
  o.x = a.x + b.x + c.x + d.x + e.x;
  o.y = a.y + b.y + c.y + d.y + e.y;
  o.z = a.z + b.z + c.z + d.z + e.z;
  o.w = a.w + b.w + c.w + d.w + e.w;
  reinterpret_cast<float4*>(out0)[i] = o;
}

extern "C" void kernel_launch(void* const* d_in, const int* in_sizes, int n_in,
                              void* d_out, int out_size, void* d_ws, size_t ws_size,
                              hipStream_t stream) {
  const float* hidden    = (const float*)d_in[0];
  const float* cstate_in = (const float*)d_in[1];
  const float* sstate_in = (const float*)d_in[2];
  const float* norm_w    = (const float*)d_in[3];
  const float* w_in      = (const float*)d_in[4];
  const float* conv_w    = (const float*)d_in[5];
  const float* conv_b    = (const float*)d_in[6];
  const float* A_log     = (const float*)d_in[7];
  const float* D_param   = (const float*)d_in[8];
  const float* dt_bias   = (const float*)d_in[9];
  const float* ssm_nw    = (const float*)d_in[10];
  const float* w_out     = (const float*)d_in[11];

  float* out0 = (float*)d_out;                    // [256,4096]
  float* out1 = out0 + (size_t)Sq * Hd;           // [10240,3]
  float* out2 = out1 + (size_t)CONV_DIM * 3;      // [128,64,128]

  ushort* h_hi  = (ushort*)d_ws;                              // 2 MB
  ushort* h_lo  = h_hi + (size_t)Sq * Hd;                     // 2 MB
  float* proj   = (float*)(h_lo + (size_t)Sq * Hd);           // 19 MB
  float* y_conv = proj + (size_t)Sq * IN_OUT;                 // 10.5 MB
  float* dtp    = y_conv + (size_t)Sq * CONV_DIM;             // 128 KB
  float* ys     = dtp + (size_t)Sq * NH;                      // 8 MB
  ushort* ys_h  = (ushort*)(ys + (size_t)Sq * D_INNER);       // 4 MB
  float* dtfix  = (float*)(ys_h + (size_t)Sq * D_INNER);      // 512 KB
  float* oppart = proj;   // out_proj partials alias proj (dead after gated_norm_k)

  // 1. RMSNorm -> fp16 hi/lo
  rmsnorm_k<<<Sq, 256, 0, stream>>>(hidden, norm_w, h_hi, h_lo);
  // 2. in_proj: proj[256,18560] = h @ w_in^T  (580 blocks, paired row-tiles, z=1)
  gemm_stream<<<dim3(2 * (IN_OUT / 64), 1, 1), 256, 0, stream>>>(
      h_hi, w_in, proj, IN_OUT, Hd, Hd, Sq);
  // 2b. dt columns, compensated fp16 (~f32), split-K x4 -> dtfix partials (32 blocks)
  gemm_mfma<64, true><<<dim3(4, 2, 4), 256, 0, stream>>>(
      h_hi, h_lo, w_in, dtfix, NH, Hd, Hd / 4, DT_COL0, Sq);
  // 3. conv + silu
  conv_silu_k<<<dim3(CONV_DIM / 256, Sq), 256, 0, stream>>>(proj, cstate_in, conv_w, conv_b, y_conv);
  // 4. conv_state_out
  conv_state_out_k<<<(CONV_DIM * 3) / 256, 256, 0, stream>>>(proj, out1);
  // 5. dt: reduce partials + softplus
  dt_k<<<(Sq * NH) / 256, 256, 0, stream>>>(dtfix, dt_bias, dtp);
  // 6. SSM scan (2 blocks per head)
  ssm_scan_k<<<NH * 2, 256, 0, stream>>>(y_conv, dtp, sstate_in, A_log, D_param, ys, out2);
  // 7. gated + grouped RMSNorm -> fp16 A for out_proj  (proj dead after this)
  gated_norm_k<<<dim3(Sq, Gg), 256, 0, stream>>>(ys, proj, ssm_nw, ys_h);
  // 8. out_proj split-K x4 -> partials (512 blocks), into aliased proj space
  gemm_stream<<<dim3(2 * (Hd / 64), 1, 4), 256, 0, stream>>>(
      ys_h, w_out, oppart, Hd, D_INNER, D_INNER / 4, Sq);
  // 9. reduce 4 partials + residual
  reduce_out_k<<<(Sq * Hd / 4) / 256, 256, 0, stream>>>(oppart, hidden, out0);
}

// Round 8
// 386.825 us; speedup vs baseline: 1.5621x; 1.4063x over previous
//
#include <hip/hip_runtime.h>
#include <hip/hip_bf16.h>

// Problem constants
#define Sq 256
#define Hd 4096
#define NH 128
#define Pd 64
#define Gg 8
#define Nn 128
#define D_INNER 8192            // NH*P
#define D_STATE 1024            // G*N
#define CONV_DIM 10240          // D_INNER + 2*D_STATE
#define IN_OUT 18560            // D_INNER + CONV_DIM + NH
#define DT_COL0 18432           // D_INNER + CONV_DIM (start of dt columns)
#define EPSI 1e-6f

typedef _Float16 f16x8 __attribute__((ext_vector_type(8)));
typedef _Float16 f16x2 __attribute__((ext_vector_type(2)));
typedef float f32x4 __attribute__((ext_vector_type(4)));

__device__ inline ushort f2h(float f) {
  _Float16 h = (_Float16)f;
  return __builtin_bit_cast(ushort, h);
}
__device__ inline ushort f2h_lo(float f, ushort hi) {
  float hf = (float)__builtin_bit_cast(_Float16, hi);
  _Float16 l = (_Float16)(f - hf);
  return __builtin_bit_cast(ushort, l);
}
__device__ inline f16x2 pkrtz(float a, float b) {
  return __builtin_bit_cast(f16x2, __builtin_amdgcn_cvt_pkrtz(a, b));
}

// ---------------- RMSNorm (input) -> fp16 hi + lo ----------------
__global__ __launch_bounds__(256) void rmsnorm_k(const float* __restrict__ x,
                                                 const float* __restrict__ w,
                                                 ushort* __restrict__ h_hi,
                                                 ushort* __restrict__ h_lo) {
  int s = blockIdx.x, t = threadIdx.x;
  const float4* row = reinterpret_cast<const float4*>(x + (size_t)s * Hd);
  const float4* wv  = reinterpret_cast<const float4*>(w);
  float4 v[4];
  float ss = 0.f;
#pragma unroll
  for (int i = 0; i < 4; i++) {
    v[i] = row[t + i * 256];
    ss += v[i].x * v[i].x + v[i].y * v[i].y + v[i].z * v[i].z + v[i].w * v[i].w;
  }
#pragma unroll
  for (int off = 32; off > 0; off >>= 1) ss += __shfl_xor(ss, off);
  __shared__ float red[4];
  if ((t & 63) == 0) red[t >> 6] = ss;
  __syncthreads();
  ss = red[0] + red[1] + red[2] + red[3];
  float scale = rsqrtf(ss * (1.f / (float)Hd) + EPSI);
  ushort4* hh = reinterpret_cast<ushort4*>(h_hi + (size_t)s * Hd);
  ushort4* hl = reinterpret_cast<ushort4*>(h_lo + (size_t)s * Hd);
#pragma unroll
  for (int i = 0; i < 4; i++) {
    float4 wi = wv[t + i * 256];
    float f0 = v[i].x * scale * wi.x, f1 = v[i].y * scale * wi.y;
    float f2 = v[i].z * scale * wi.z, f3 = v[i].w * scale * wi.w;
    ushort4 oh, ol;
    oh.x = f2h(f0); ol.x = f2h_lo(f0, oh.x);
    oh.y = f2h(f1); ol.y = f2h_lo(f1, oh.y);
    oh.z = f2h(f2); ol.z = f2h_lo(f2, oh.z);
    oh.w = f2h(f3); ol.w = f2h_lo(f3, oh.w);
    hh[t + i * 256] = oh;
    hl[t + i * 256] = ol;
  }
}

// ============ global_load_lds GEMM: C[256,ldc](z-plane) = A_f16[256,K] @ f16(B_f32)^T ====
// BM=256(all M), BN=64, BK=32. 512 threads = 8 waves (4 row-groups x 2 col-groups).
// A staged fp16 [256][32] linear+src-swizzled; B staged f32 [64][32] linear+src-swizzled.
// Double-buffered, 2-phase: issue DMA(next) -> compute(cur) -> __syncthreads (drain).
__global__ __launch_bounds__(512) void gemm_gl(const ushort* __restrict__ A,
                                               const float* __restrict__ B,
                                               float* __restrict__ C,
                                               int ldc, int K, int kLen) {
  __shared__ __align__(16) ushort As[2][256 * 32];   // 16 KB each
  __shared__ __align__(16) float  Bsf[2][64 * 32];   // 8 KB each
  int t = threadIdx.x;
  int wave = t >> 6, lane = t & 63;
  int wr = wave & 3, wc = wave >> 2;
  int frow = lane & 15;
  int gq = lane >> 4;                  // 0..3 (k-granule of fragment)
  int bcol = blockIdx.x * 64;
  int kStart = blockIdx.z * kLen;
  C += (size_t)blockIdx.z * Sq * ldc;  // split-K partial plane

  // --- source pointers with granule swizzle baked into the GLOBAL address ---
  int ar = t >> 2;                                   // 0..127 (A row for issue 1)
  int aq = (t & 3) ^ (ar & 3);                       // swizzled 16B-granule (8 f16)
  const ushort* ApG0 = A + (size_t)ar * K + kStart + aq * 8;
  const ushort* ApG1 = ApG0 + (size_t)128 * K;       // rows 128..255, same swizzle
  int br = t >> 3;                                   // 0..63 (B row)
  int bq = (t & 7) ^ (br & 7);                       // swizzled 16B-granule (4 f32)
  const float* BpG = B + (size_t)(bcol + br) * K + kStart + bq * 4;

  // wave-uniform LDS destinations (DMA writes base + lane*16)
  char* dstA0 = (char*)&As[0][0] + wave * 1024;
  char* dstA1 = (char*)&As[0][0] + 8192 + wave * 1024;
  char* dstB  = (char*)&Bsf[0][0] + wave * 1024;

  f32x4 acc[4][2] = {};

#define STAGE(p, kk) { \
    __builtin_amdgcn_global_load_lds( \
        (const __attribute__((address_space(1))) void*)(ApG0 + (kk)), \
        (__attribute__((address_space(3))) void*)(dstA0 + (p) * 16384), 16, 0, 0); \
    __builtin_amdgcn_global_load_lds( \
        (const __attribute__((address_space(1))) void*)(ApG1 + (kk)), \
        (__attribute__((address_space(3))) void*)(dstA1 + (p) * 16384), 16, 0, 0); \
    __builtin_amdgcn_global_load_lds( \
        (const __attribute__((address_space(1))) void*)(BpG + (kk)), \
        (__attribute__((address_space(3))) void*)(dstB + (p) * 8192), 16, 0, 0); }

  STAGE(0, 0)
  __syncthreads();
  int cur = 0;
  for (int ki = 0; ki < kLen; ki += 32) {
    if (ki + 32 < kLen) STAGE(cur ^ 1, ki + 32)
    // ---- fragments (swizzled reads) + MFMA ----
    f16x8 af[4], bf[2];
#pragma unroll
    for (int m = 0; m < 4; ++m) {
      int row = wr * 64 + m * 16 + frow;
      af[m] = *(const f16x8*)((const char*)&As[cur][0] + row * 64 + ((gq ^ (frow & 3)) * 16));
    }
#pragma unroll
    for (int n = 0; n < 2; ++n) {
      int row = wc * 32 + n * 16 + frow;
      int g0 = 2 * gq, r7 = frow & 7;
      float4 b0 = *(const float4*)((const char*)&Bsf[cur][0] + row * 128 + ((g0 ^ r7) * 16));
      float4 b1 = *(const float4*)((const char*)&Bsf[cur][0] + row * 128 + (((g0 + 1) ^ r7) * 16));
      union { f16x2 h2[4]; f16x8 h8; } u;
      u.h2[0] = pkrtz(b0.x, b0.y);
      u.h2[1] = pkrtz(b0.z, b0.w);
      u.h2[2] = pkrtz(b1.x, b1.y);
      u.h2[3] = pkrtz(b1.z, b1.w);
      bf[n] = u.h8;
    }
#pragma unroll
    for (int m = 0; m < 4; ++m)
#pragma unroll
      for (int n = 0; n < 2; ++n)
        acc[m][n] = __builtin_amdgcn_mfma_f32_16x16x32_f16(af[m], bf[n], acc[m][n], 0, 0, 0);
    __syncthreads();
    cur ^= 1;
  }
#undef STAGE

  // Epilogue: C/D layout col=lane&15, row=(lane>>4)*4+r
#pragma unroll
  for (int m = 0; m < 4; ++m) {
    int row0 = wr * 64 + m * 16 + (lane >> 4) * 4;
#pragma unroll
    for (int n = 0; n < 2; ++n) {
      int col = bcol + wc * 32 + n * 16 + frow;
#pragma unroll
      for (int r = 0; r < 4; ++r)
        C[(size_t)(row0 + r) * ldc + col] = acc[m][n][r];
    }
  }
}

// ---------------- reg-staged MFMA GEMM (dt-fixup, compensated fp16) ----
template<int BN, bool SPLIT>
__global__ __launch_bounds__(256) void gemm_mfma(const ushort* __restrict__ A_hi,
                                                 const ushort* __restrict__ A_lo,
                                                 const float* __restrict__ B,
                                                 float* __restrict__ C,
                                                 int ldc, int K, int kLen,
                                                 int bcol0, int M) {
  constexpr int BK = 64;
  constexpr int LDA = 72;
  constexpr int N_REP = BN / 32;
  constexpr int BQN = (BN == 128) ? 8 : 4;
  __shared__ __align__(16) ushort As[64 * LDA];
  __shared__ __align__(16) ushort Bs[BN * LDA];
  __shared__ __align__(16) ushort AsL[SPLIT ? 64 * LDA : 1];
  __shared__ __align__(16) ushort BsL[SPLIT ? BN * LDA : 1];

  int t = threadIdx.x;
  int wave = t >> 6, lane = t & 63;
  int wr = wave >> 1, wc = wave & 1;
  int frow = lane & 15, fk = (lane >> 4) * 8;
  int rowBase = blockIdx.x * 64;
  int bcol = bcol0 + blockIdx.y * BN;
  int ccol = blockIdx.y * BN;
  int kStart = blockIdx.z * kLen;
  C += (size_t)blockIdx.z * M * ldc;

  int arow = t >> 2, ak = (t & 3) * 16;
  const ushort* Ap  = A_hi + (size_t)(rowBase + arow) * K + ak;
  const ushort* ApL = SPLIT ? (A_lo + (size_t)(rowBase + arow) * K + ak) : nullptr;

  int brow, bq;
  if constexpr (BN == 128) { brow = t >> 1; bq = (t & 1) * 32; }
  else                     { brow = t >> 2; bq = (t & 3) * 16; }
  const float* Bp = B + (size_t)(bcol + brow) * K + bq;

  f32x4 acc[2][N_REP] = {};
  uint4 aPre[2], aPreL[2];
  float4 bPre[BQN];

  auto loadK = [&](int kk) {
    aPre[0] = *reinterpret_cast<const uint4*>(Ap + kk);
    aPre[1] = *reinterpret_cast<const uint4*>(Ap + kk + 8);
    if constexpr (SPLIT) {
      aPreL[0] = *reinterpret_cast<const uint4*>(ApL + kk);
      aPreL[1] = *reinterpret_cast<const uint4*>(ApL + kk + 8);
    }
#pragma unroll
    for (int j = 0; j < BQN; ++j)
      bPre[j] = *reinterpret_cast<const float4*>(Bp + kk + j * 4);
  };

  loadK(kStart);
  for (int ki = 0; ki < kLen; ki += BK) {
    __syncthreads();
    *reinterpret_cast<uint4*>(&As[arow * LDA + ak])     = aPre[0];
    *reinterpret_cast<uint4*>(&As[arow * LDA + ak + 8]) = aPre[1];
    if constexpr (SPLIT) {
      *reinterpret_cast<uint4*>(&AsL[arow * LDA + ak])     = aPreL[0];
      *reinterpret_cast<uint4*>(&AsL[arow * LDA + ak + 8]) = aPreL[1];
    }
    {
      ushort hb[BQN * 4];
      ushort lb[SPLIT ? BQN * 4 : 1];
      const float* bf = reinterpret_cast<const float*>(bPre);
#pragma unroll
      for (int j = 0; j < BQN * 4; ++j) {
        hb[j] = f2h(bf[j]);
        if constexpr (SPLIT) lb[j] = f2h_lo(bf[j], hb[j]);
      }
#pragma unroll
      for (int j = 0; j < BQN / 2; ++j)
        *reinterpret_cast<uint4*>(&Bs[brow * LDA + bq + j * 8]) =
            reinterpret_cast<const uint4*>(hb)[j];
      if constexpr (SPLIT) {
#pragma unroll
        for (int j = 0; j < BQN / 2; ++j)
          *reinterpret_cast<uint4*>(&BsL[brow * LDA + bq + j * 8]) =
              reinterpret_cast<const uint4*>(lb)[j];
      }
    }
    __syncthreads();
    if (ki + BK < kLen) loadK(kStart + ki + BK);
    f16x8 af[2][2], bfv[N_REP][2];
    f16x8 afL[SPLIT ? 2 : 1][2], bfL[SPLIT ? N_REP : 1][2];
#pragma unroll
    for (int m = 0; m < 2; ++m)
#pragma unroll
      for (int kh = 0; kh < 2; ++kh) {
        af[m][kh] = *reinterpret_cast<const f16x8*>(
            &As[(wr * 32 + m * 16 + frow) * LDA + kh * 32 + fk]);
        if constexpr (SPLIT)
          afL[m][kh] = *reinterpret_cast<const f16x8*>(
              &AsL[(wr * 32 + m * 16 + frow) * LDA + kh * 32 + fk]);
      }
#pragma unroll
    for (int n = 0; n < N_REP; ++n)
#pragma unroll
      for (int kh = 0; kh < 2; ++kh) {
        bfv[n][kh] = *reinterpret_cast<const f16x8*>(
            &Bs[(wc * (BN / 2) + n * 16 + frow) * LDA + kh * 32 + fk]);
        if constexpr (SPLIT)
          bfL[n][kh] = *reinterpret_cast<const f16x8*>(
              &BsL[(wc * (BN / 2) + n * 16 + frow) * LDA + kh * 32 + fk]);
      }
#pragma unroll
    for (int kh = 0; kh < 2; ++kh)
#pragma unroll
      for (int m = 0; m < 2; ++m)
#pragma unroll
        for (int n = 0; n < N_REP; ++n) {
          acc[m][n] = __builtin_amdgcn_mfma_f32_16x16x32_f16(af[m][kh], bfv[n][kh], acc[m][n], 0, 0, 0);
          if constexpr (SPLIT) {
            acc[m][n] = __builtin_amdgcn_mfma_f32_16x16x32_f16(af[m][kh], bfL[n][kh], acc[m][n], 0, 0, 0);
            acc[m][n] = __builtin_amdgcn_mfma_f32_16x16x32_f16(afL[m][kh], bfv[n][kh], acc[m][n], 0, 0, 0);
          }
        }
  }

#pragma unroll
  for (int m = 0; m < 2; ++m) {
    int row0 = rowBase + wr * 32 + m * 16 + (lane >> 4) * 4;
#pragma unroll
    for (int n = 0; n < N_REP; ++n) {
      int col = ccol + wc * (BN / 2) + n * 16 + frow;
#pragma unroll
      for (int r = 0; r < 4; ++r)
        C[(size_t)(row0 + r) * ldc + col] = acc[m][n][r];
    }
  }
}

// ---------------- reduce 2 in_proj split-K planes (in place into plane0) ------
__global__ __launch_bounds__(256) void reduce2_k(float* __restrict__ p0,
                                                 const float* __restrict__ p1) {
  int i = blockIdx.x * 256 + threadIdx.x;   // f4 index
  float4 a = reinterpret_cast<const float4*>(p0)[i];
  float4 b = reinterpret_cast<const float4*>(p1)[i];
  a.x += b.x; a.y += b.y; a.z += b.z; a.w += b.w;
  reinterpret_cast<float4*>(p0)[i] = a;
}

// ---------------- Conv (K=4) + SiLU ----------------
__global__ __launch_bounds__(256) void conv_silu_k(const float* __restrict__ proj,
                                                   const float* __restrict__ cstate,
                                                   const float* __restrict__ cw,
                                                   const float* __restrict__ cb,
                                                   float* __restrict__ y) {
  int c = blockIdx.x * 256 + threadIdx.x;  // 0..10239
  int s = blockIdx.y;                      // 0..255
  float acc = cb[c];
  float4 w4 = *reinterpret_cast<const float4*>(cw + c * 4);
  float wj[4] = {w4.x, w4.y, w4.z, w4.w};
#pragma unroll
  for (int j = 0; j < 4; j++) {
    int si = s + j - 3;
    float v = (si < 0) ? cstate[c * 3 + (si + 3)]
                       : proj[(size_t)si * IN_OUT + D_INNER + c];
    acc += wj[j] * v;
  }
  float sig = 1.f / (1.f + expf(-acc));
  y[(size_t)s * CONV_DIM + c] = acc * sig;
}

// ---------------- conv_state_out ----------------
__global__ __launch_bounds__(256) void conv_state_out_k(const float* __restrict__ proj,
                                                        float* __restrict__ out1) {
  int idx = blockIdx.x * 256 + threadIdx.x;  // < 30720
  int c = idx / 3, tt = idx % 3;
  out1[idx] = proj[(size_t)(Sq - 3 + tt) * IN_OUT + D_INNER + c];
}

// ---------------- dt: reduce 4 split-K partials + bias -> softplus ----------------
__global__ __launch_bounds__(256) void dt_k(const float* __restrict__ dtfix,
                                            const float* __restrict__ dt_bias,
                                            float* __restrict__ dtp) {
  int idx = blockIdx.x * 256 + threadIdx.x;  // 32768 = 256*128
  int hh = idx & 127;
  float v = dtfix[idx] + dtfix[32768 + idx] + dtfix[65536 + idx] + dtfix[98304 + idx]
            + dt_bias[hh];
  dtp[idx] = (v > 20.f) ? v : log1pf(expf(v));
}

// ---------------- SSM scan (chunked LDS staging, 2 blocks per head) ----------------
#define CS 16
__global__ __launch_bounds__(256) void ssm_scan_k(const float* __restrict__ y_conv,
                                                  const float* __restrict__ dtp,
                                                  const float* __restrict__ sstate_in,
                                                  const float* __restrict__ A_log,
                                                  const float* __restrict__ D_param,
                                                  float* __restrict__ ys_out,
                                                  float* __restrict__ sstate_out) {
  int h = blockIdx.x >> 1;
  int pb = (blockIdx.x & 1) * 32;
  int t = threadIdx.x;
  int ng = t & 7, pl = t >> 3;
  int g = h >> 4;  // rep = NH/G = 16
  float A = -expf(A_log[h]);
  float Dp = D_param[h];

  float st[16];
  {
    const float* sp = sstate_in + ((size_t)h * Pd + pb + pl) * Nn + ng * 16;
#pragma unroll
    for (int i = 0; i < 16; i += 4) {
      float4 v = *reinterpret_cast<const float4*>(sp + i);
      st[i] = v.x; st[i + 1] = v.y; st[i + 2] = v.z; st[i + 3] = v.w;
    }
  }

  __shared__ float ybuf[CS][296];   // [0..31]=x(local), [32..159]=B, [160..287]=C
  __shared__ float dts[CS];
  int lr = t >> 4;
  int lc = t & 15;

  for (int ch = 0; ch < Sq / CS; ++ch) {
    int s0 = ch * CS;
    __syncthreads();
    const float* rowp = y_conv + (size_t)(s0 + lr) * CONV_DIM;
#pragma unroll
    for (int j = 0; j < 5; ++j) {
      int c = lc + 16 * j;
      if (c < 72) {
        const float* src;
        if (c < 8)       src = rowp + h * 64 + pb + c * 4;
        else if (c < 40) src = rowp + D_INNER + g * 128 + (c - 8) * 4;
        else             src = rowp + D_INNER + D_STATE + g * 128 + (c - 40) * 4;
        *reinterpret_cast<float4*>(&ybuf[lr][c * 4]) = *reinterpret_cast<const float4*>(src);
      }
    }
    if (t < CS) dts[t] = dtp[(s0 + t) * NH + h];
    __syncthreads();

#pragma unroll 4
    for (int stp = 0; stp < CS; ++stp) {
      float dt = dts[stp];
      float dA = expf(dt * A);
      float x0 = ybuf[stp][pl];
      float dtx = dt * x0;
      float y0 = 0.f;
#pragma unroll
      for (int i = 0; i < 16; ++i) {
        float b = ybuf[stp][32 + ng * 16 + i];
        float c = ybuf[stp][160 + ng * 16 + i];
        st[i] = st[i] * dA + dtx * b;
        y0 += st[i] * c;
      }
      y0 += __shfl_xor(y0, 1); y0 += __shfl_xor(y0, 2); y0 += __shfl_xor(y0, 4);
      if (ng == 0)
        ys_out[(size_t)(s0 + stp) * D_INNER + h * 64 + pb + pl] = y0 + Dp * x0;
    }
  }

  float* so = sstate_out + ((size_t)h * Pd + pb + pl) * Nn + ng * 16;
#pragma unroll
  for (int i = 0; i < 16; i += 4)
    *reinterpret_cast<float4*>(so + i) = make_float4(st[i], st[i + 1], st[i + 2], st[i + 3]);
}

// ---------------- gate*silu + grouped RMSNorm -> fp16 ----------------
__global__ __launch_bounds__(256) void gated_norm_k(const float* __restrict__ ys,
                                                    const float* __restrict__ proj,
                                                    const float* __restrict__ w,
                                                    ushort* __restrict__ out_h) {
  int s = blockIdx.x, g = blockIdx.y, t = threadIdx.x;
  float vals[4];
  float ss = 0.f;
#pragma unroll
  for (int i = 0; i < 4; i++) {
    int d = g * 1024 + i * 256 + t;
    float gate = proj[(size_t)s * IN_OUT + d];
    float v = ys[(size_t)s * D_INNER + d] * (gate / (1.f + expf(-gate)));
    vals[i] = v;
    ss += v * v;
  }
#pragma unroll
  for (int off = 32; off > 0; off >>= 1) ss += __shfl_xor(ss, off);
  __shared__ float red[4];
  if ((t & 63) == 0) red[t >> 6] = ss;
  __syncthreads();
  ss = red[0] + red[1] + red[2] + red[3];
  float scale = rsqrtf(ss * (1.f / 1024.f) + EPSI);
#pragma unroll
  for (int i = 0; i < 4; i++) {
    int d = g * 1024 + i * 256 + t;
    out_h[(size_t)s * D_INNER + d] = f2h(vals[i] * scale * w[d]);
  }
}

// ---------------- out reduce: out0 = sum of 8 planes + hidden ----------------
__global__ __launch_bounds__(256) void reduce_out_k(const float* __restrict__ p,
                                                    const float* __restrict__ hidden,
                                                    float* __restrict__ out0) {
  int i = blockIdx.x * 256 + threadIdx.x;
  const int PL = Sq * Hd / 4;
  float4 o = reinterpret_cast<const float4*>(hidden)[i];
#pragma unroll
  for (int z = 0; z < 8; ++z) {
    float4 a = reinterpret_cast<const float4*>(p)[i + z * PL];
    o.x += a.x; o.y += a.y; o.z += a.z; o.w += a.w;
  }
  reinterpret_cast<float4*>(out0)[i] = o;
}

extern "C" void kernel_launch(void* const* d_in, const int* in_sizes, int n_in,
                              void* d_out, int out_size, void* d_ws, size_t ws_size,
                              hipStream_t stream) {
  const float* hidden    = (const float*)d_in[0];
  const float* cstate_in = (const float*)d_in[1];
  const float* sstate_in = (const float*)d_in[2];
  const float* norm_w    = (const float*)d_in[3];
  const float* w_in      = (const float*)d_in[4];
  const float* conv_w    = (const float*)d_in[5];
  const float* conv_b    = (const float*)d_in[6];
  const float* A_log     = (const float*)d_in[7];
  const float* D_param   = (const float*)d_in[8];
  const float* dt_bias   = (const float*)d_in[9];
  const float* ssm_nw    = (const float*)d_in[10];
  const float* w_out     = (const float*)d_in[11];

  float* out0 = (float*)d_out;                    // [256,4096]
  float* out1 = out0 + (size_t)Sq * Hd;           // [10240,3]
  float* out2 = out1 + (size_t)CONV_DIM * 3;      // [128,64,128]

  ushort* h_hi  = (ushort*)d_ws;                              // 2 MB
  ushort* h_lo  = h_hi + (size_t)Sq * Hd;                     // 2 MB
  float* proj   = (float*)(h_lo + (size_t)Sq * Hd);           // 19 MB
  float* y_conv = proj + (size_t)Sq * IN_OUT;                 // 10.5 MB (in_proj plane1 aliases this pre-conv)
  float* dtp    = y_conv + (size_t)Sq * CONV_DIM;             // 128 KB
  float* ys     = dtp + (size_t)Sq * NH;                      // 8 MB
  ushort* ys_h  = (ushort*)(ys + (size_t)Sq * D_INNER);       // 4 MB
  float* dtfix  = (float*)(ys_h + (size_t)Sq * D_INNER);      // 512 KB
  float* oppart = proj;   // out_proj 8 planes (32 MB) alias proj..ys (all dead by then)

  // 1. RMSNorm -> fp16 hi/lo
  rmsnorm_k<<<Sq, 256, 0, stream>>>(hidden, norm_w, h_hi, h_lo);
  // 2. in_proj via global_load_lds GEMM: split-K x2 (plane1 lands at y_conv region)
  gemm_gl<<<dim3(IN_OUT / 64, 1, 2), 512, 0, stream>>>(h_hi, w_in, proj, IN_OUT, Hd, Hd / 2);
  // 2r. reduce split-K planes into proj
  reduce2_k<<<(Sq * IN_OUT / 4) / 256, 256, 0, stream>>>(proj, proj + (size_t)Sq * IN_OUT);
  // 2b. dt columns, compensated fp16 (~f32), split-K x4 -> dtfix partials (32 blocks)
  gemm_mfma<64, true><<<dim3(4, 2, 4), 256, 0, stream>>>(
      h_hi, h_lo, w_in, dtfix, NH, Hd, Hd / 4, DT_COL0, Sq);
  // 3. conv + silu
  conv_silu_k<<<dim3(CONV_DIM / 256, Sq), 256, 0, stream>>>(proj, cstate_in, conv_w, conv_b, y_conv);
  // 4. conv_state_out
  conv_state_out_k<<<(CONV_DIM * 3) / 256, 256, 0, stream>>>(proj, out1);
  // 5. dt: reduce partials + softplus
  dt_k<<<(Sq * NH) / 256, 256, 0, stream>>>(dtfix, dt_bias, dtp);
  // 6. SSM scan (2 blocks per head)
  ssm_scan_k<<<NH * 2, 256, 0, stream>>>(y_conv, dtp, sstate_in, A_log, D_param, ys, out2);
  // 7. gated + grouped RMSNorm -> fp16 A for out_proj
  gated_norm_k<<<dim3(Sq, Gg), 256, 0, stream>>>(ys, proj, ssm_nw, ys_h);
  // 8. out_proj via global_load_lds GEMM: split-K x8 -> 8 planes in dead proj space
  gemm_gl<<<dim3(Hd / 64, 1, 8), 512, 0, stream>>>(ys_h, w_out, oppart, Hd, D_INNER, D_INNER / 8);
  // 9. reduce 8 partials + residual
  reduce_out_k<<<(Sq * Hd / 4) / 256, 256, 0, stream>>>(oppart, hidden, out0);
}

// Round 9
// 382.399 us; speedup vs baseline: 1.5802x; 1.0116x over previous
//
#include <hip/hip_runtime.h>
#include <hip/hip_bf16.h>

// Problem constants
#define Sq 256
#define Hd 4096
#define NH 128
#define Pd 64
#define Gg 8
#define Nn 128
#define D_INNER 8192            // NH*P
#define D_STATE 1024            // G*N
#define CONV_DIM 10240          // D_INNER + 2*D_STATE
#define IN_OUT 18560            // D_INNER + CONV_DIM + NH
#define DT_COL0 18432           // D_INNER + CONV_DIM (start of dt columns)
#define EPSI 1e-6f

typedef _Float16 f16x8 __attribute__((ext_vector_type(8)));
typedef _Float16 f16x2 __attribute__((ext_vector_type(2)));
typedef float f32x4 __attribute__((ext_vector_type(4)));

__device__ inline ushort f2h(float f) {
  _Float16 h = (_Float16)f;
  return __builtin_bit_cast(ushort, h);
}
__device__ inline ushort f2h_lo(float f, ushort hi) {
  float hf = (float)__builtin_bit_cast(_Float16, hi);
  _Float16 l = (_Float16)(f - hf);
  return __builtin_bit_cast(ushort, l);
}
__device__ inline f16x2 pkrtz(float a, float b) {
  return __builtin_bit_cast(f16x2, __builtin_amdgcn_cvt_pkrtz(a, b));
}

// ---------------- RMSNorm (input) -> fp16 hi + lo ----------------
__global__ __launch_bounds__(256) void rmsnorm_k(const float* __restrict__ x,
                                                 const float* __restrict__ w,
                                                 ushort* __restrict__ h_hi,
                                                 ushort* __restrict__ h_lo) {
  int s = blockIdx.x, t = threadIdx.x;
  const float4* row = reinterpret_cast<const float4*>(x + (size_t)s * Hd);
  const float4* wv  = reinterpret_cast<const float4*>(w);
  float4 v[4];
  float ss = 0.f;
#pragma unroll
  for (int i = 0; i < 4; i++) {
    v[i] = row[t + i * 256];
    ss += v[i].x * v[i].x + v[i].y * v[i].y + v[i].z * v[i].z + v[i].w * v[i].w;
  }
#pragma unroll
  for (int off = 32; off > 0; off >>= 1) ss += __shfl_xor(ss, off);
  __shared__ float red[4];
  if ((t & 63) == 0) red[t >> 6] = ss;
  __syncthreads();
  ss = red[0] + red[1] + red[2] + red[3];
  float scale = rsqrtf(ss * (1.f / (float)Hd) + EPSI);
  ushort4* hh = reinterpret_cast<ushort4*>(h_hi + (size_t)s * Hd);
  ushort4* hl = reinterpret_cast<ushort4*>(h_lo + (size_t)s * Hd);
#pragma unroll
  for (int i = 0; i < 4; i++) {
    float4 wi = wv[t + i * 256];
    float f0 = v[i].x * scale * wi.x, f1 = v[i].y * scale * wi.y;
    float f2 = v[i].z * scale * wi.z, f3 = v[i].w * scale * wi.w;
    ushort4 oh, ol;
    oh.x = f2h(f0); ol.x = f2h_lo(f0, oh.x);
    oh.y = f2h(f1); ol.y = f2h_lo(f1, oh.y);
    oh.z = f2h(f2); ol.z = f2h_lo(f2, oh.z);
    oh.w = f2h(f3); ol.w = f2h_lo(f3, oh.w);
    hh[t + i * 256] = oh;
    hl[t + i * 256] = ol;
  }
}

// ============ global_load_lds GEMM: C[256,ldc](z-plane) = A_f16[256,K] @ f16(B_f32)^T ====
// BM=256(all M), BN=64, BK=32. 512 threads = 8 waves (4 row-groups x 2 col-groups).
// A staged fp16 [256][32] linear+src-swizzled; B staged f32 [64][32] linear+src-swizzled.
// T3/T4: double buffer, counted vmcnt (never 0 in steady state), raw s_barrier.
__global__ __launch_bounds__(512) void gemm_gl(const ushort* __restrict__ A,
                                               const float* __restrict__ B,
                                               float* __restrict__ C,
                                               int ldc, int K, int kLen) {
  __shared__ __align__(16) ushort As[2][256 * 32];   // 16 KB each
  __shared__ __align__(16) float  Bsf[2][64 * 32];   // 8 KB each
  int t = threadIdx.x;
  int wave = t >> 6, lane = t & 63;
  int wr = wave & 3, wc = wave >> 2;
  int frow = lane & 15;
  int gq = lane >> 4;                  // 0..3 (k-granule of fragment)
  int bcol = blockIdx.x * 64;
  int kStart = blockIdx.z * kLen;
  C += (size_t)blockIdx.z * Sq * ldc;  // split-K partial plane

  // --- source pointers with granule swizzle baked into the GLOBAL address ---
  int ar = t >> 2;                                   // 0..127 (A row for issue 1)
  int aq = (t & 3) ^ (ar & 3);                       // swizzled 16B-granule (8 f16)
  const ushort* ApG0 = A + (size_t)ar * K + kStart + aq * 8;
  const ushort* ApG1 = ApG0 + (size_t)128 * K;       // rows 128..255, same swizzle
  int br = t >> 3;                                   // 0..63 (B row)
  int bq = (t & 7) ^ (br & 7);                       // swizzled 16B-granule (4 f32)
  const float* BpG = B + (size_t)(bcol + br) * K + kStart + bq * 4;

  // wave-uniform LDS destinations (DMA writes base + lane*16)
  char* dstA0 = (char*)&As[0][0] + wave * 1024;
  char* dstA1 = (char*)&As[0][0] + 8192 + wave * 1024;
  char* dstB  = (char*)&Bsf[0][0] + wave * 1024;

  f32x4 acc[4][2] = {};
  const int NT = kLen / 32;

#define STAGE(p, kk) { \
    __builtin_amdgcn_global_load_lds( \
        (const __attribute__((address_space(1))) void*)(ApG0 + (kk)), \
        (__attribute__((address_space(3))) void*)(dstA0 + (p) * 16384), 16, 0, 0); \
    __builtin_amdgcn_global_load_lds( \
        (const __attribute__((address_space(1))) void*)(ApG1 + (kk)), \
        (__attribute__((address_space(3))) void*)(dstA1 + (p) * 16384), 16, 0, 0); \
    __builtin_amdgcn_global_load_lds( \
        (const __attribute__((address_space(1))) void*)(BpG + (kk)), \
        (__attribute__((address_space(3))) void*)(dstB + (p) * 8192), 16, 0, 0); }
#define SB() __builtin_amdgcn_sched_barrier(0)

  // Prologue: tiles 0 and 1 in flight (3 loads each).
  STAGE(0, 0)
  STAGE(1, 32)
  int cur = 0;
  for (int i = 0; i < NT; ++i) {
    // Wait for tile i only (tile i+1 stays in flight); then cross barrier.
    if (i + 1 < NT) { asm volatile("s_waitcnt vmcnt(3)" ::: "memory"); }
    else            { asm volatile("s_waitcnt vmcnt(0)" ::: "memory"); }
    SB();
    __builtin_amdgcn_s_barrier();
    SB();
    // ---- fragments (swizzled reads) + MFMA, tile i from buf[cur] ----
    f16x8 af[4], bf[2];
#pragma unroll
    for (int m = 0; m < 4; ++m) {
      int row = wr * 64 + m * 16 + frow;
      af[m] = *(const f16x8*)((const char*)&As[cur][0] + row * 64 + ((gq ^ (frow & 3)) * 16));
    }
#pragma unroll
    for (int n = 0; n < 2; ++n) {
      int row = wc * 32 + n * 16 + frow;
      int g0 = 2 * gq, r7 = frow & 7;
      float4 b0 = *(const float4*)((const char*)&Bsf[cur][0] + row * 128 + ((g0 ^ r7) * 16));
      float4 b1 = *(const float4*)((const char*)&Bsf[cur][0] + row * 128 + (((g0 + 1) ^ r7) * 16));
      union { f16x2 h2[4]; f16x8 h8; } u;
      u.h2[0] = pkrtz(b0.x, b0.y);
      u.h2[1] = pkrtz(b0.z, b0.w);
      u.h2[2] = pkrtz(b1.x, b1.y);
      u.h2[3] = pkrtz(b1.z, b1.w);
      bf[n] = u.h8;
    }
#pragma unroll
    for (int m = 0; m < 4; ++m)
#pragma unroll
      for (int n = 0; n < 2; ++n)
        acc[m][n] = __builtin_amdgcn_mfma_f32_16x16x32_f16(af[m], bf[n], acc[m][n], 0, 0, 0);
    // All waves done reading buf[cur] before its DMA overwrite next.
    SB();
    __builtin_amdgcn_s_barrier();
    SB();
    if (i + 2 < NT) STAGE(cur, (i + 2) * 32)   // tile i+2 into just-freed buf[cur]
    cur ^= 1;
  }
#undef STAGE
#undef SB

  // Epilogue: C/D layout col=lane&15, row=(lane>>4)*4+r
#pragma unroll
  for (int m = 0; m < 4; ++m) {
    int row0 = wr * 64 + m * 16 + (lane >> 4) * 4;
#pragma unroll
    for (int n = 0; n < 2; ++n) {
      int col = bcol + wc * 32 + n * 16 + frow;
#pragma unroll
      for (int r = 0; r < 4; ++r)
        C[(size_t)(row0 + r) * ldc + col] = acc[m][n][r];
    }
  }
}

// ---------------- reg-staged MFMA GEMM (dt-fixup, compensated fp16) ----
template<int BN, bool SPLIT>
__global__ __launch_bounds__(256) void gemm_mfma(const ushort* __restrict__ A_hi,
                                                 const ushort* __restrict__ A_lo,
                                                 const float* __restrict__ B,
                                                 float* __restrict__ C,
                                                 int ldc, int K, int kLen,
                                                 int bcol0, int M) {
  constexpr int BK = 64;
  constexpr int LDA = 72;
  constexpr int N_REP = BN / 32;
  constexpr int BQN = (BN == 128) ? 8 : 4;
  __shared__ __align__(16) ushort As[64 * LDA];
  __shared__ __align__(16) ushort Bs[BN * LDA];
  __shared__ __align__(16) ushort AsL[SPLIT ? 64 * LDA : 1];
  __shared__ __align__(16) ushort BsL[SPLIT ? BN * LDA : 1];

  int t = threadIdx.x;
  int wave = t >> 6, lane = t & 63;
  int wr = wave >> 1, wc = wave & 1;
  int frow = lane & 15, fk = (lane >> 4) * 8;
  int rowBase = blockIdx.x * 64;
  int bcol = bcol0 + blockIdx.y * BN;
  int ccol = blockIdx.y * BN;
  int kStart = blockIdx.z * kLen;
  C += (size_t)blockIdx.z * M * ldc;

  int arow = t >> 2, ak = (t & 3) * 16;
  const ushort* Ap  = A_hi + (size_t)(rowBase + arow) * K + ak;
  const ushort* ApL = SPLIT ? (A_lo + (size_t)(rowBase + arow) * K + ak) : nullptr;

  int brow, bq;
  if constexpr (BN == 128) { brow = t >> 1; bq = (t & 1) * 32; }
  else                     { brow = t >> 2; bq = (t & 3) * 16; }
  const float* Bp = B + (size_t)(bcol + brow) * K + bq;

  f32x4 acc[2][N_REP] = {};
  uint4 aPre[2], aPreL[2];
  float4 bPre[BQN];

  auto loadK = [&](int kk) {
    aPre[0] = *reinterpret_cast<const uint4*>(Ap + kk);
    aPre[1] = *reinterpret_cast<const uint4*>(Ap + kk + 8);
    if constexpr (SPLIT) {
      aPreL[0] = *reinterpret_cast<const uint4*>(ApL + kk);
      aPreL[1] = *reinterpret_cast<const uint4*>(ApL + kk + 8);
    }
#pragma unroll
    for (int j = 0; j < BQN; ++j)
      bPre[j] = *reinterpret_cast<const float4*>(Bp + kk + j * 4);
  };

  loadK(kStart);
  for (int ki = 0; ki < kLen; ki += BK) {
    __syncthreads();
    *reinterpret_cast<uint4*>(&As[arow * LDA + ak])     = aPre[0];
    *reinterpret_cast<uint4*>(&As[arow * LDA + ak + 8]) = aPre[1];
    if constexpr (SPLIT) {
      *reinterpret_cast<uint4*>(&AsL[arow * LDA + ak])     = aPreL[0];
      *reinterpret_cast<uint4*>(&AsL[arow * LDA + ak + 8]) = aPreL[1];
    }
    {
      ushort hb[BQN * 4];
      ushort lb[SPLIT ? BQN * 4 : 1];
      const float* bf = reinterpret_cast<const float*>(bPre);
#pragma unroll
      for (int j = 0; j < BQN * 4; ++j) {
        hb[j] = f2h(bf[j]);
        if constexpr (SPLIT) lb[j] = f2h_lo(bf[j], hb[j]);
      }
#pragma unroll
      for (int j = 0; j < BQN / 2; ++j)
        *reinterpret_cast<uint4*>(&Bs[brow * LDA + bq + j * 8]) =
            reinterpret_cast<const uint4*>(hb)[j];
      if constexpr (SPLIT) {
#pragma unroll
        for (int j = 0; j < BQN / 2; ++j)
          *reinterpret_cast<uint4*>(&BsL[brow * LDA + bq + j * 8]) =
              reinterpret_cast<const uint4*>(lb)[j];
      }
    }
    __syncthreads();
    if (ki + BK < kLen) loadK(kStart + ki + BK);
    f16x8 af[2][2], bfv[N_REP][2];
    f16x8 afL[SPLIT ? 2 : 1][2], bfL[SPLIT ? N_REP : 1][2];
#pragma unroll
    for (int m = 0; m < 2; ++m)
#pragma unroll
      for (int kh = 0; kh < 2; ++kh) {
        af[m][kh] = *reinterpret_cast<const f16x8*>(
            &As[(wr * 32 + m * 16 + frow) * LDA + kh * 32 + fk]);
        if constexpr (SPLIT)
          afL[m][kh] = *reinterpret_cast<const f16x8*>(
              &AsL[(wr * 32 + m * 16 + frow) * LDA + kh * 32 + fk]);
      }
#pragma unroll
    for (int n = 0; n < N_REP; ++n)
#pragma unroll
      for (int kh = 0; kh < 2; ++kh) {
        bfv[n][kh] = *reinterpret_cast<const f16x8*>(
            &Bs[(wc * (BN / 2) + n * 16 + frow) * LDA + kh * 32 + fk]);
        if constexpr (SPLIT)
          bfL[n][kh] = *reinterpret_cast<const f16x8*>(
              &BsL[(wc * (BN / 2) + n * 16 + frow) * LDA + kh * 32 + fk]);
      }
#pragma unroll
    for (int kh = 0; kh < 2; ++kh)
#pragma unroll
      for (int m = 0; m < 2; ++m)
#pragma unroll
        for (int n = 0; n < N_REP; ++n) {
          acc[m][n] = __builtin_amdgcn_mfma_f32_16x16x32_f16(af[m][kh], bfv[n][kh], acc[m][n], 0, 0, 0);
          if constexpr (SPLIT) {
            acc[m][n] = __builtin_amdgcn_mfma_f32_16x16x32_f16(af[m][kh], bfL[n][kh], acc[m][n], 0, 0, 0);
            acc[m][n] = __builtin_amdgcn_mfma_f32_16x16x32_f16(afL[m][kh], bfv[n][kh], acc[m][n], 0, 0, 0);
          }
        }
  }

#pragma unroll
  for (int m = 0; m < 2; ++m) {
    int row0 = rowBase + wr * 32 + m * 16 + (lane >> 4) * 4;
#pragma unroll
    for (int n = 0; n < N_REP; ++n) {
      int col = ccol + wc * (BN / 2) + n * 16 + frow;
#pragma unroll
      for (int r = 0; r < 4; ++r)
        C[(size_t)(row0 + r) * ldc + col] = acc[m][n][r];
    }
  }
}

// ---------------- reduce 2 in_proj split-K planes (in place into plane0) ------
__global__ __launch_bounds__(256) void reduce2_k(float* __restrict__ p0,
                                                 const float* __restrict__ p1) {
  int i = blockIdx.x * 256 + threadIdx.x;   // f4 index
  float4 a = reinterpret_cast<const float4*>(p0)[i];
  float4 b = reinterpret_cast<const float4*>(p1)[i];
  a.x += b.x; a.y += b.y; a.z += b.z; a.w += b.w;
  reinterpret_cast<float4*>(p0)[i] = a;
}

// ---------------- Conv (K=4) + SiLU ----------------
__global__ __launch_bounds__(256) void conv_silu_k(const float* __restrict__ proj,
                                                   const float* __restrict__ cstate,
                                                   const float* __restrict__ cw,
                                                   const float* __restrict__ cb,
                                                   float* __restrict__ y) {
  int c = blockIdx.x * 256 + threadIdx.x;  // 0..10239
  int s = blockIdx.y;                      // 0..255
  float acc = cb[c];
  float4 w4 = *reinterpret_cast<const float4*>(cw + c * 4);
  float wj[4] = {w4.x, w4.y, w4.z, w4.w};
#pragma unroll
  for (int j = 0; j < 4; j++) {
    int si = s + j - 3;
    float v = (si < 0) ? cstate[c * 3 + (si + 3)]
                       : proj[(size_t)si * IN_OUT + D_INNER + c];
    acc += wj[j] * v;
  }
  float sig = 1.f / (1.f + expf(-acc));
  y[(size_t)s * CONV_DIM + c] = acc * sig;
}

// ---------------- conv_state_out ----------------
__global__ __launch_bounds__(256) void conv_state_out_k(const float* __restrict__ proj,
                                                        float* __restrict__ out1) {
  int idx = blockIdx.x * 256 + threadIdx.x;  // < 30720
  int c = idx / 3, tt = idx % 3;
  out1[idx] = proj[(size_t)(Sq - 3 + tt) * IN_OUT + D_INNER + c];
}

// ---------------- dt: reduce 4 split-K partials + bias -> softplus ----------------
__global__ __launch_bounds__(256) void dt_k(const float* __restrict__ dtfix,
                                            const float* __restrict__ dt_bias,
                                            float* __restrict__ dtp) {
  int idx = blockIdx.x * 256 + threadIdx.x;  // 32768 = 256*128
  int hh = idx & 127;
  float v = dtfix[idx] + dtfix[32768 + idx] + dtfix[65536 + idx] + dtfix[98304 + idx]
            + dt_bias[hh];
  dtp[idx] = (v > 20.f) ? v : log1pf(expf(v));
}

// ---------------- SSM scan (chunked LDS staging, 2 blocks per head) ----------------
#define CS 16
__global__ __launch_bounds__(256) void ssm_scan_k(const float* __restrict__ y_conv,
                                                  const float* __restrict__ dtp,
                                                  const float* __restrict__ sstate_in,
                                                  const float* __restrict__ A_log,
                                                  const float* __restrict__ D_param,
                                                  float* __restrict__ ys_out,
                                                  float* __restrict__ sstate_out) {
  int h = blockIdx.x >> 1;
  int pb = (blockIdx.x & 1) * 32;
  int t = threadIdx.x;
  int ng = t & 7, pl = t >> 3;
  int g = h >> 4;  // rep = NH/G = 16
  float A = -expf(A_log[h]);
  float Dp = D_param[h];

  float st[16];
  {
    const float* sp = sstate_in + ((size_t)h * Pd + pb + pl) * Nn + ng * 16;
#pragma unroll
    for (int i = 0; i < 16; i += 4) {
      float4 v = *reinterpret_cast<const float4*>(sp + i);
      st[i] = v.x; st[i + 1] = v.y; st[i + 2] = v.z; st[i + 3] = v.w;
    }
  }

  __shared__ float ybuf[CS][296];   // [0..31]=x(local), [32..159]=B, [160..287]=C
  __shared__ float dts[CS];
  int lr = t >> 4;
  int lc = t & 15;

  for (int ch = 0; ch < Sq / CS; ++ch) {
    int s0 = ch * CS;
    __syncthreads();
    const float* rowp = y_conv + (size_t)(s0 + lr) * CONV_DIM;
#pragma unroll
    for (int j = 0; j < 5; ++j) {
      int c = lc + 16 * j;
      if (c < 72) {
        const float* src;
        if (c < 8)       src = rowp + h * 64 + pb + c * 4;
        else if (c < 40) src = rowp + D_INNER + g * 128 + (c - 8) * 4;
        else             src = rowp + D_INNER + D_STATE + g * 128 + (c - 40) * 4;
        *reinterpret_cast<float4*>(&ybuf[lr][c * 4]) = *reinterpret_cast<const float4*>(src);
      }
    }
    if (t < CS) dts[t] = dtp[(s0 + t) * NH + h];
    __syncthreads();

#pragma unroll 4
    for (int stp = 0; stp < CS; ++stp) {
      float dt = dts[stp];
      float dA = expf(dt * A);
      float x0 = ybuf[stp][pl];
      float dtx = dt * x0;
      float y0 = 0.f;
#pragma unroll
      for (int i = 0; i < 16; ++i) {
        float b = ybuf[stp][32 + ng * 16 + i];
        float c = ybuf[stp][160 + ng * 16 + i];
        st[i] = st[i] * dA + dtx * b;
        y0 += st[i] * c;
      }
      y0 += __shfl_xor(y0, 1); y0 += __shfl_xor(y0, 2); y0 += __shfl_xor(y0, 4);
      if (ng == 0)
        ys_out[(size_t)(s0 + stp) * D_INNER + h * 64 + pb + pl] = y0 + Dp * x0;
    }
  }

  float* so = sstate_out + ((size_t)h * Pd + pb + pl) * Nn + ng * 16;
#pragma unroll
  for (int i = 0; i < 16; i += 4)
    *reinterpret_cast<float4*>(so + i) = make_float4(st[i], st[i + 1], st[i + 2], st[i + 3]);
}

// ---------------- gate*silu + grouped RMSNorm -> fp16 ----------------
__global__ __launch_bounds__(256) void gated_norm_k(const float* __restrict__ ys,
                                                    const float* __restrict__ proj,
                                                    const float* __restrict__ w,
                                                    ushort* __restrict__ out_h) {
  int s = blockIdx.x, g = blockIdx.y, t = threadIdx.x;
  float vals[4];
  float ss = 0.f;
#pragma unroll
  for (int i = 0; i < 4; i++) {
    int d = g * 1024 + i * 256 + t;
    float gate = proj[(size_t)s * IN_OUT + d];
    float v = ys[(size_t)s * D_INNER + d] * (gate / (1.f + expf(-gate)));
    vals[i] = v;
    ss += v * v;
  }
#pragma unroll
  for (int off = 32; off > 0; off >>= 1) ss += __shfl_xor(ss, off);
  __shared__ float red[4];
  if ((t & 63) == 0) red[t >> 6] = ss;
  __syncthreads();
  ss = red[0] + red[1] + red[2] + red[3];
  float scale = rsqrtf(ss * (1.f / 1024.f) + EPSI);
#pragma unroll
  for (int i = 0; i < 4; i++) {
    int d = g * 1024 + i * 256 + t;
    out_h[(size_t)s * D_INNER + d] = f2h(vals[i] * scale * w[d]);
  }
}

// ---------------- out reduce: out0 = sum of 8 planes + hidden ----------------
__global__ __launch_bounds__(256) void reduce_out_k(const float* __restrict__ p,
                                                    const float* __restrict__ hidden,
                                                    float* __restrict__ out0) {
  int i = blockIdx.x * 256 + threadIdx.x;
  const int PL = Sq * Hd / 4;
  float4 o = reinterpret_cast<const float4*>(hidden)[i];
#pragma unroll
  for (int z = 0; z < 8; ++z) {
    float4 a = reinterpret_cast<const float4*>(p)[i + z * PL];
    o.x += a.x; o.y += a.y; o.z += a.z; o.w += a.w;
  }
  reinterpret_cast<float4*>(out0)[i] = o;
}

extern "C" void kernel_launch(void* const* d_in, const int* in_sizes, int n_in,
                              void* d_out, int out_size, void* d_ws, size_t ws_size,
                              hipStream_t stream) {
  const float* hidden    = (const float*)d_in[0];
  const float* cstate_in = (const float*)d_in[1];
  const float* sstate_in = (const float*)d_in[2];
  const float* norm_w    = (const float*)d_in[3];
  const float* w_in      = (const float*)d_in[4];
  const float* conv_w    = (const float*)d_in[5];
  const float* conv_b    = (const float*)d_in[6];
  const float* A_log     = (const float*)d_in[7];
  const float* D_param   = (const float*)d_in[8];
  const float* dt_bias   = (const float*)d_in[9];
  const float* ssm_nw    = (const float*)d_in[10];
  const float* w_out     = (const float*)d_in[11];

  float* out0 = (float*)d_out;                    // [256,4096]
  float* out1 = out0 + (size_t)Sq * Hd;           // [10240,3]
  float* out2 = out1 + (size_t)CONV_DIM * 3;      // [128,64,128]

  ushort* h_hi  = (ushort*)d_ws;                              // 2 MB
  ushort* h_lo  = h_hi + (size_t)Sq * Hd;                     // 2 MB
  float* proj   = (float*)(h_lo + (size_t)Sq * Hd);           // 19 MB
  float* y_conv = proj + (size_t)Sq * IN_OUT;                 // 10.5 MB (in_proj plane1 aliases this pre-conv)
  float* dtp    = y_conv + (size_t)Sq * CONV_DIM;             // 128 KB
  float* ys     = dtp + (size_t)Sq * NH;                      // 8 MB
  ushort* ys_h  = (ushort*)(ys + (size_t)Sq * D_INNER);       // 4 MB
  float* dtfix  = (float*)(ys_h + (size_t)Sq * D_INNER);      // 512 KB
  float* oppart = proj;   // out_proj 8 planes (32 MB) alias proj..ys (all dead by then)

  // 1. RMSNorm -> fp16 hi/lo
  rmsnorm_k<<<Sq, 256, 0, stream>>>(hidden, norm_w, h_hi, h_lo);
  // 2. in_proj via global_load_lds GEMM: split-K x2 (plane1 lands at y_conv region)
  gemm_gl<<<dim3(IN_OUT / 64, 1, 2), 512, 0, stream>>>(h_hi, w_in, proj, IN_OUT, Hd, Hd / 2);
  // 2r. reduce split-K planes into proj
  reduce2_k<<<(Sq * IN_OUT / 4) / 256, 256, 0, stream>>>(proj, proj + (size_t)Sq * IN_OUT);
  // 2b. dt columns, compensated fp16 (~f32), split-K x4 -> dtfix partials (32 blocks)
  gemm_mfma<64, true><<<dim3(4, 2, 4), 256, 0, stream>>>(
      h_hi, h_lo, w_in, dtfix, NH, Hd, Hd / 4, DT_COL0, Sq);
  // 3. conv + silu
  conv_silu_k<<<dim3(CONV_DIM / 256, Sq), 256, 0, stream>>>(proj, cstate_in, conv_w, conv_b, y_conv);
  // 4. conv_state_out
  conv_state_out_k<<<(CONV_DIM * 3) / 256, 256, 0, stream>>>(proj, out1);
  // 5. dt: reduce partials + softplus
  dt_k<<<(Sq * NH) / 256, 256, 0, stream>>>(dtfix, dt_bias, dtp);
  // 6. SSM scan (2 blocks per head)
  ssm_scan_k<<<NH * 2, 256, 0, stream>>>(y_conv, dtp, sstate_in, A_log, D_param, ys, out2);
  // 7. gated + grouped RMSNorm -> fp16 A for out_proj
  gated_norm_k<<<dim3(Sq, Gg), 256, 0, stream>>>(ys, proj, ssm_nw, ys_h);
  // 8. out_proj via global_load_lds GEMM: split-K x8 -> 8 planes in dead proj space
  gemm_gl<<<dim3(Hd / 64, 1, 8), 512, 0, stream>>>(ys_h, w_out, oppart, Hd, D_INNER, D_INNER / 8);
  // 9. reduce 8 partials + residual
  reduce_out_k<<<(Sq * Hd / 4) / 256, 256, 0, stream>>>(oppart, hidden, out0);
}